// Round 3
// baseline (1939.805 us; speedup 1.0000x reference)
//
#include <hip/hip_runtime.h>
#include <hip/hip_bf16.h>

typedef __attribute__((ext_vector_type(8))) short short8;
typedef __attribute__((ext_vector_type(4))) float f32x4;

#define THREADS 512
#define MFMA(a, b, c) __builtin_amdgcn_mfma_f32_16x16x32_bf16((a), (b), (c), 0, 0, 0)

static __device__ __forceinline__ unsigned short f2bf(float x) {
    __hip_bfloat16 h = __float2bfloat16(x);
    return __builtin_bit_cast(unsigned short, h);
}
static __device__ __forceinline__ unsigned pk2(float a, float b) {
    return (unsigned)f2bf(a) | ((unsigned)f2bf(b) << 16);
}
static __device__ __forceinline__ float bflo(unsigned u) {
    unsigned v = u << 16; return __builtin_bit_cast(float, v);
}
static __device__ __forceinline__ float bfhi(unsigned u) {
    unsigned v = u & 0xffff0000u; return __builtin_bit_cast(float, v);
}
static __device__ __forceinline__ float fast_tanh(float x) {
    float e = __builtin_amdgcn_exp2f(x * 2.885390081777927f);
    float r = __builtin_amdgcn_rcpf(e + 1.0f);
    return fmaf(-2.0f, r, 1.0f);
}
static __device__ __forceinline__ short8 cvt8(float4 a, float4 b) {
    short8 r;
    r[0] = (short)f2bf(a.x); r[1] = (short)f2bf(a.y);
    r[2] = (short)f2bf(a.z); r[3] = (short)f2bf(a.w);
    r[4] = (short)f2bf(b.x); r[5] = (short)f2bf(b.y);
    r[6] = (short)f2bf(b.z); r[7] = (short)f2bf(b.w);
    return r;
}
// async global -> LDS, 16B/lane, sc0=1 (bypass CU L1: slots are re-read every step)
static __device__ __forceinline__ void gl_lds16(const unsigned short* g, unsigned short* l) {
    __builtin_amdgcn_global_load_lds(
        (const __attribute__((address_space(1))) unsigned int*)g,
        (__attribute__((address_space(3))) unsigned int*)l, 16, 0, 1);
}
static __device__ __forceinline__ int ldf(int* p) {
    return __hip_atomic_load(p, __ATOMIC_ACQUIRE, __HIP_MEMORY_SCOPE_AGENT);
}
static __device__ __forceinline__ void stf(int* p, int v) {
    __hip_atomic_store(p, v, __ATOMIC_RELEASE, __HIP_MEMORY_SCOPE_AGENT);
}

// Load a 32-col x 512-k bf16 B-panel into registers.
// B-frag (16x16x32, round-1-verified): lane holds W[colbase + nt*16 + (l&15)][kt*32 + (l>>4)*8 + e]
#define LOAD_PANEL(W, CB, KT_OF_J)                                              \
    do {                                                                        \
        _Pragma("unroll")                                                       \
        for (int j = 0; j < 16; ++j) {                                          \
            const int kt_ = (KT_OF_J);                                          \
            const float* p0_ = (W) + (size_t)((CB) + c) * 512 + kt_ * 32 + q * 8;       \
            const float* p1_ = (W) + (size_t)((CB) + 16 + c) * 512 + kt_ * 32 + q * 8;  \
            float4 a0_ = *(const float4*)p0_, b0_ = *(const float4*)(p0_ + 4);  \
            float4 a1_ = *(const float4*)p1_, b1_ = *(const float4*)(p1_ + 4);  \
            bw0[j] = cvt8(a0_, b0_);                                            \
            bw1[j] = cvt8(a1_, b1_);                                            \
        }                                                                       \
    } while (0)

__global__ __launch_bounds__(THREADS, 2) void toroidal(
    const float* __restrict__ x,
    const float* __restrict__ Wx_w, const float* __restrict__ wxb,
    const float* __restrict__ Wh_w, const float* __restrict__ whb,
    const float* __restrict__ Hd_w, const float* __restrict__ hdb,
    const float* __restrict__ gamma_p, const float* __restrict__ alphas,
    const int* __restrict__ steps_p,
    float* __restrict__ out, int* __restrict__ flags)
{
    __shared__ __align__(16) unsigned short sfrag[32768];  // 64KB: A-frags [mt4][kt16][lane64][e8], XOR-swizzled
    __shared__ __align__(16) unsigned int   hist[16384];   // 64KB: 2 slots x 4 quads x 512 tid x 4 u32

    const int tid = threadIdx.x;
    const int w = tid >> 6;
    const int l = tid & 63;
    const int q = l >> 4;
    const int c = l & 15;

    const int bi  = blockIdx.x;
    const int mu  = (bi >> 3) & 1;                 // pair member
    const int grp = (bi & 7) * 16 + (bi >> 4);     // 0..127, pair {bi, bi^8} same XCD
    const int pb  = bi ^ 8;
    const int rows0 = grp * 64;

    int* prod = flags;
    int* cons = flags + 256;

    // exchange slots live inside d_out: group g owns out rows [64g,64g+64) = 64KB; member halves 32KB
    unsigned short* piece_me = (unsigned short*)out + (size_t)grp * 32768 + mu * 16384;
    unsigned short* piece_pa = (unsigned short*)out + (size_t)grp * 32768 + (1 - mu) * 16384;

    const float gm = gamma_p[0];
    const float g1 = gm * alphas[0], g2 = gm * alphas[1], g3 = gm * alphas[2];
    const int nsteps = steps_p[0];

    const int colbase = mu * 256 + w * 32;         // this wave's hidden cols
    const float bias0 = wxb[colbase + c] + whb[colbase + c];
    const float bias1 = wxb[colbase + 16 + c] + whb[colbase + 16 + c];
    const float hb0 = hdb[w * 32 + c], hb1 = hdb[w * 32 + 16 + c];

    const int roff = (l * 8) ^ (((l >> 4) & 3) << 3);   // swizzled A-read offset (shorts)
    const int k0own = 8 * mu, k0par = 8 * (1 - mu);

    short8 bw0[16], bw1[16];

    // ================= xproj: B regs <- Wx panel (natural kt order) =================
    LOAD_PANEL(Wx_w, colbase, j);

    f32x4 acc[4][2];
    #pragma unroll
    for (int mt = 0; mt < 4; ++mt) {
        acc[mt][0] = (f32x4){0.f, 0.f, 0.f, 0.f};
        acc[mt][1] = (f32x4){0.f, 0.f, 0.f, 0.f};
    }
    #pragma unroll
    for (int pass = 0; pass < 2; ++pass) {
        __syncthreads();
        // stage 64 rows x 256 k of x as f32 A-frags into sfrag
        #pragma unroll
        for (int j2 = 0; j2 < 8; ++j2) {
            int r = j2 * 8 + w;
            int kloc = l * 4;
            float4 v = *(const float4*)(x + (size_t)(rows0 + r) * 512 + pass * 256 + kloc);
            int mtx = r >> 4, ktl = kloc >> 5;
            int lane2 = (r & 15) + 16 * ((kloc >> 3) & 3);
            float* dst = (float*)sfrag + ((mtx * 8 + ktl) * 64 + lane2) * 8 + (kloc & 7);
            *(float4*)dst = v;
        }
        __syncthreads();
        #pragma unroll
        for (int j = 0; j < 8; ++j) {
            #pragma unroll
            for (int mt = 0; mt < 4; ++mt) {
                const float* fp = (const float*)sfrag + ((mt * 8 + j) * 64 + l) * 8;
                float4 u0 = *(const float4*)fp;
                float4 u1 = *(const float4*)(fp + 4);
                short8 a = cvt8(u0, u1);
                acc[mt][0] = MFMA(a, bw0[pass * 8 + j], acc[mt][0]);
                acc[mt][1] = MFMA(a, bw1[pass * 8 + j], acc[mt][1]);
            }
        }
    }
    __syncthreads();   // xproj reads done before step-1 scatter overwrites sfrag

    // xp packed bf16 (pairs over i)
    unsigned xpk[4][2][2];
    #pragma unroll
    for (int mt = 0; mt < 4; ++mt)
        #pragma unroll
        for (int nt = 0; nt < 2; ++nt) {
            float b = nt ? bias1 : bias0;
            xpk[mt][nt][0] = pk2(acc[mt][nt][0] + b, acc[mt][nt][1] + b);
            xpk[mt][nt][1] = pk2(acc[mt][nt][2] + b, acc[mt][nt][3] + b);
        }

    // ================= B regs <- Wh panel (own-half-first kt order) =================
    LOAD_PANEL(Wh_w, colbase, (j < 8 ? k0own + j : k0par + (j - 8)));

    // zero state
    uint4 z4 = {0u, 0u, 0u, 0u};
    #pragma unroll
    for (int sb = 0; sb < 8; ++sb) *(uint4*)&hist[(sb * 512 + tid) * 4] = z4;
    float s[4][2][4];
    unsigned h0[4][2][2];
    #pragma unroll
    for (int mt = 0; mt < 4; ++mt)
        #pragma unroll
        for (int nt = 0; nt < 2; ++nt) {
            acc[mt][nt] = (f32x4){0.f, 0.f, 0.f, 0.f};
            h0[mt][nt][0] = h0[mt][nt][1] = 0u;
            #pragma unroll
            for (int i = 0; i < 4; ++i) s[mt][nt][i] = 0.f;
        }

    // ================= recurrence =================
    // iteration t: acc = s_{t-1}@Wh^T (from GEMM t-1); recirc lags: h0 = s_{t-2},
    // hist[t&1] = s_{t-3}, hist[(t+1)&1] = s_{t-4} (round-1-verified lag structure)
    for (int t = 1; t <= nsteps; ++t) {
        const int sA = t & 1, sB = sA ^ 1;
        #pragma unroll
        for (int mt = 0; mt < 4; ++mt) {
            uint4 hA = *(uint4*)&hist[((sA * 4 + mt) * 512 + tid) * 4];
            uint4 hB = *(uint4*)&hist[((sB * 4 + mt) * 512 + tid) * 4];
            uint4 nB;
            #pragma unroll
            for (int nt = 0; nt < 2; ++nt)
                #pragma unroll
                for (int pi = 0; pi < 2; ++pi) {
                    unsigned u1 = h0[mt][nt][pi];
                    unsigned u2 = ((unsigned*)&hA)[nt * 2 + pi];
                    unsigned u3 = ((unsigned*)&hB)[nt * 2 + pi];
                    unsigned ux = xpk[mt][nt][pi];
                    float p0 = acc[mt][nt][pi * 2] + bflo(ux)
                             + g1 * bflo(u1) + g2 * bflo(u2) + g3 * bflo(u3);
                    float p1 = acc[mt][nt][pi * 2 + 1] + bfhi(ux)
                             + g1 * bfhi(u1) + g2 * bfhi(u2) + g3 * bfhi(u3);
                    float so0 = s[mt][nt][pi * 2], so1 = s[mt][nt][pi * 2 + 1];
                    float sn0 = 0.5f * so0 + 0.5f * fast_tanh(p0);
                    float sn1 = 0.5f * so1 + 0.5f * fast_tanh(p1);
                    s[mt][nt][pi * 2] = sn0; s[mt][nt][pi * 2 + 1] = sn1;
                    ((unsigned*)&nB)[nt * 2 + pi] = u1;       // s_{t-2} -> slot (becomes s_{t'-4})
                    h0[mt][nt][pi] = pk2(so0, so1);           // s_{t-1} for next iteration
                }
            *(uint4*)&hist[((sB * 4 + mt) * 512 + tid) * 4] = nB;
            acc[mt][0] = (f32x4){0.f, 0.f, 0.f, 0.f};
            acc[mt][1] = (f32x4){0.f, 0.f, 0.f, 0.f};
        }

        // wait: partner consumed our piece t-1 (slot free), per-wave poll
        if (l == 0) { while (ldf(&cons[pb]) < t - 1) __builtin_amdgcn_s_sleep(1); }
        __builtin_amdgcn_sched_barrier(0);

        // scatter s_t: own LDS region (swizzled) + global piece (pre-swizzled for linear gl_lds)
        #pragma unroll
        for (int mt = 0; mt < 4; ++mt)
            #pragma unroll
            for (int nt = 0; nt < 2; ++nt)
                #pragma unroll
                for (int i = 0; i < 4; ++i) {
                    int lam = q * 4 + i + 16 * (nt * 2 + (c >> 3));
                    int wo = (lam * 8 + (c & 7)) ^ (((lam >> 4) & 3) << 3);
                    unsigned short v = f2bf(s[mt][nt][i]);
                    sfrag[(mt * 16 + k0own + w) * 512 + wo] = v;
                    piece_me[(mt * 8 + w) * 512 + wo] = v;
                }
        __syncthreads();                                   // drains vmcnt+lgkm, barrier
        if (tid == 0) stf(&prod[bi], t);
        if (t == nsteps) break;

        // own-half GEMM (kt = k0own + j), hides exchange latency
        #pragma unroll
        for (int j = 0; j < 8; ++j) {
            const int kt = k0own + j;
            short8 a0 = *(const short8*)&sfrag[(0 * 16 + kt) * 512 + roff];
            short8 a1 = *(const short8*)&sfrag[(1 * 16 + kt) * 512 + roff];
            short8 a2 = *(const short8*)&sfrag[(2 * 16 + kt) * 512 + roff];
            short8 a3 = *(const short8*)&sfrag[(3 * 16 + kt) * 512 + roff];
            acc[0][0] = MFMA(a0, bw0[j], acc[0][0]); acc[0][1] = MFMA(a0, bw1[j], acc[0][1]);
            acc[1][0] = MFMA(a1, bw0[j], acc[1][0]); acc[1][1] = MFMA(a1, bw1[j], acc[1][1]);
            acc[2][0] = MFMA(a2, bw0[j], acc[2][0]); acc[2][1] = MFMA(a2, bw1[j], acc[2][1]);
            acc[3][0] = MFMA(a3, bw0[j], acc[3][0]); acc[3][1] = MFMA(a3, bw1[j], acc[3][1]);
        }

        // partner piece ready? stage it (linear gl_lds; data pre-swizzled at store)
        if (l == 0) { while (ldf(&prod[pb]) < t) __builtin_amdgcn_s_sleep(1); }
        __builtin_amdgcn_sched_barrier(0);
        {
            const int mtg = w >> 1;
            #pragma unroll
            for (int i2 = 0; i2 < 4; ++i2) {
                const int ktl = 4 * (w & 1) + i2;
                gl_lds16(piece_pa + (mtg * 8 + ktl) * 512 + l * 8,
                         &sfrag[(mtg * 16 + k0par + ktl) * 512]);
            }
        }
        __syncthreads();                                   // drains gl_lds vmcnt, barrier
        if (tid == 0) stf(&cons[bi], t);

        // partner-half GEMM (kt = k0par + (j-8))
        #pragma unroll
        for (int j = 8; j < 16; ++j) {
            const int kt = k0par + (j - 8);
            short8 a0 = *(const short8*)&sfrag[(0 * 16 + kt) * 512 + roff];
            short8 a1 = *(const short8*)&sfrag[(1 * 16 + kt) * 512 + roff];
            short8 a2 = *(const short8*)&sfrag[(2 * 16 + kt) * 512 + roff];
            short8 a3 = *(const short8*)&sfrag[(3 * 16 + kt) * 512 + roff];
            acc[0][0] = MFMA(a0, bw0[j], acc[0][0]); acc[0][1] = MFMA(a0, bw1[j], acc[0][1]);
            acc[1][0] = MFMA(a1, bw0[j], acc[1][0]); acc[1][1] = MFMA(a1, bw1[j], acc[1][1]);
            acc[2][0] = MFMA(a2, bw0[j], acc[2][0]); acc[2][1] = MFMA(a2, bw1[j], acc[2][1]);
            acc[3][0] = MFMA(a3, bw0[j], acc[3][0]); acc[3][1] = MFMA(a3, bw1[j], acc[3][1]);
        }
    }

    // ================= head: out = s_final @ Head^T + Head_b =================
    // final partner piece
    if (l == 0) { while (ldf(&prod[pb]) < nsteps) __builtin_amdgcn_s_sleep(1); }
    __builtin_amdgcn_sched_barrier(0);
    {
        const int mtg = w >> 1;
        #pragma unroll
        for (int i2 = 0; i2 < 4; ++i2) {
            const int ktl = 4 * (w & 1) + i2;
            gl_lds16(piece_pa + (mtg * 8 + ktl) * 512 + l * 8,
                     &sfrag[(mtg * 16 + k0par + ktl) * 512]);
        }
    }
    // B regs <- Head panel (same own-first kt order; block mu covers rows [32mu,32mu+32), all 256 cols)
    LOAD_PANEL(Hd_w, w * 32, (j < 8 ? k0own + j : k0par + (j - 8)));
    __syncthreads();
    if (tid == 0) stf(&cons[bi], nsteps);

    f32x4 ah[2][2];
    ah[0][0] = (f32x4){0.f, 0.f, 0.f, 0.f}; ah[0][1] = (f32x4){0.f, 0.f, 0.f, 0.f};
    ah[1][0] = (f32x4){0.f, 0.f, 0.f, 0.f}; ah[1][1] = (f32x4){0.f, 0.f, 0.f, 0.f};
    #pragma unroll
    for (int j = 0; j < 16; ++j) {
        const int kt = (j < 8) ? k0own + j : k0par + (j - 8);
        short8 a0 = *(const short8*)&sfrag[((2 * mu + 0) * 16 + kt) * 512 + roff];
        short8 a1 = *(const short8*)&sfrag[((2 * mu + 1) * 16 + kt) * 512 + roff];
        ah[0][0] = MFMA(a0, bw0[j], ah[0][0]); ah[0][1] = MFMA(a0, bw1[j], ah[0][1]);
        ah[1][0] = MFMA(a1, bw0[j], ah[1][0]); ah[1][1] = MFMA(a1, bw1[j], ah[1][1]);
    }

    // partner must be done reading our slot before we overwrite it with final output
    if (l == 0) { while (ldf(&cons[pb]) < nsteps) __builtin_amdgcn_s_sleep(1); }
    __builtin_amdgcn_sched_barrier(0);
    #pragma unroll
    for (int mtL = 0; mtL < 2; ++mtL)
        #pragma unroll
        for (int i = 0; i < 4; ++i) {
            int r = rows0 + 32 * mu + mtL * 16 + q * 4 + i;
            out[(size_t)r * 256 + w * 32 + c]      = ah[mtL][0][i] + hb0;
            out[(size_t)r * 256 + w * 32 + 16 + c] = ah[mtL][1][i] + hb1;
        }
}

extern "C" void kernel_launch(void* const* d_in, const int* in_sizes, int n_in,
                              void* d_out, int out_size, void* d_ws, size_t ws_size,
                              hipStream_t stream) {
    (void)n_in; (void)out_size;
    const float* x    = (const float*)d_in[0];
    const float* Wx_w = (const float*)d_in[1];
    const float* Wx_b = (const float*)d_in[2];
    const float* Wh_w = (const float*)d_in[3];
    const float* Wh_b = (const float*)d_in[4];
    const float* Hd_w = (const float*)d_in[5];
    const float* Hd_b = (const float*)d_in[6];
    const float* gma  = (const float*)d_in[7];
    const float* alp  = (const float*)d_in[8];
    const int*   stp  = (const int*)d_in[9];
    float* out = (float*)d_out;

    if (ws_size < 4096) return;
    int* flags = (int*)d_ws;
    hipMemsetAsync(flags, 0, 4096, stream);    // prod[256] + cons[256], reset every launch

    int batch = in_sizes[0] / 512;             // 8192
    int nblk  = batch / 32;                    // 256 blocks = 128 pairs
    toroidal<<<nblk, THREADS, 0, stream>>>(x, Wx_w, Wx_b, Wh_w, Wh_b, Hd_w, Hd_b,
                                           gma, alp, stp, out, flags);
}

// Round 4
// 1787.337 us; speedup vs baseline: 1.0853x; 1.0853x over previous
//
#include <hip/hip_runtime.h>
#include <hip/hip_bf16.h>

typedef __attribute__((ext_vector_type(8))) short short8;
typedef __attribute__((ext_vector_type(4))) float f32x4;

#define THREADS 512
#define MFMA(a, b, c) __builtin_amdgcn_mfma_f32_16x16x32_bf16((a), (b), (c), 0, 0, 0)

static __device__ __forceinline__ unsigned short f2bf(float x) {
    __hip_bfloat16 h = __float2bfloat16(x);
    return __builtin_bit_cast(unsigned short, h);
}
static __device__ __forceinline__ unsigned pk2(float a, float b) {
    return (unsigned)f2bf(a) | ((unsigned)f2bf(b) << 16);
}
static __device__ __forceinline__ float bflo(unsigned u) {
    unsigned v = u << 16; return __builtin_bit_cast(float, v);
}
static __device__ __forceinline__ float bfhi(unsigned u) {
    unsigned v = u & 0xffff0000u; return __builtin_bit_cast(float, v);
}
static __device__ __forceinline__ float fast_tanh(float x) {
    float e = __builtin_amdgcn_exp2f(x * 2.885390081777927f);
    float r = __builtin_amdgcn_rcpf(e + 1.0f);
    return fmaf(-2.0f, r, 1.0f);
}
static __device__ __forceinline__ short8 cvt8(float4 a, float4 b) {
    short8 r;
    r[0] = (short)f2bf(a.x); r[1] = (short)f2bf(a.y);
    r[2] = (short)f2bf(a.z); r[3] = (short)f2bf(a.w);
    r[4] = (short)f2bf(b.x); r[5] = (short)f2bf(b.y);
    r[6] = (short)f2bf(b.z); r[7] = (short)f2bf(b.w);
    return r;
}
// async global -> LDS, 16B/lane, sc0=1 (bypass CU L1: partner data is fresh in L2)
static __device__ __forceinline__ void gl_lds16(const unsigned short* g, unsigned short* l) {
    __builtin_amdgcn_global_load_lds(
        (const __attribute__((address_space(1))) unsigned int*)g,
        (__attribute__((address_space(3))) unsigned int*)l, 16, 0, 1);
}
static __device__ __forceinline__ int ldf(int* p) {
    return __hip_atomic_load(p, __ATOMIC_ACQUIRE, __HIP_MEMORY_SCOPE_AGENT);
}
static __device__ __forceinline__ void stf(int* p, int v) {
    __hip_atomic_store(p, v, __ATOMIC_RELEASE, __HIP_MEMORY_SCOPE_AGENT);
}
#define WAITV0() asm volatile("s_waitcnt vmcnt(0)" ::: "memory")

// Load a 32-col x 512-k bf16 B-panel into registers.
// B-frag (16x16x32, round-1-verified): lane holds W[colbase + nt*16 + (l&15)][kt*32 + (l>>4)*8 + e]
#define LOAD_PANEL(W, CB, KT_OF_J)                                              \
    do {                                                                        \
        _Pragma("unroll")                                                       \
        for (int j = 0; j < 16; ++j) {                                          \
            const int kt_ = (KT_OF_J);                                          \
            const float* p0_ = (W) + (size_t)((CB) + c) * 512 + kt_ * 32 + q * 8;       \
            const float* p1_ = (W) + (size_t)((CB) + 16 + c) * 512 + kt_ * 32 + q * 8;  \
            float4 a0_ = *(const float4*)p0_, b0_ = *(const float4*)(p0_ + 4);  \
            float4 a1_ = *(const float4*)p1_, b1_ = *(const float4*)(p1_ + 4);  \
            bw0[j] = cvt8(a0_, b0_);                                            \
            bw1[j] = cvt8(a1_, b1_);                                            \
        }                                                                       \
    } while (0)

__global__ __launch_bounds__(THREADS, 1) void toroidal(
    const float* __restrict__ x,
    const float* __restrict__ Wx_w, const float* __restrict__ wxb,
    const float* __restrict__ Wh_w, const float* __restrict__ whb,
    const float* __restrict__ Hd_w, const float* __restrict__ hdb,
    const float* __restrict__ gamma_p, const float* __restrict__ alphas,
    const int* __restrict__ steps_p,
    float* __restrict__ out, int* __restrict__ flags)
{
    __shared__ __align__(16) unsigned short sfrag[32768];  // 64KB: A-frags [mt4][kt16][lane64][e8]
    __shared__ __align__(16) unsigned int   hist[16384];   // 64KB: 2 slots x 4 mt x 512 tid x 4 u32

    const int tid = threadIdx.x;
    const int w = tid >> 6;
    const int l = tid & 63;
    const int q = l >> 4;
    const int c = l & 15;

    const int bi  = blockIdx.x;
    const int mu  = (bi >> 3) & 1;                 // pair member
    const int grp = (bi & 7) * 16 + (bi >> 4);     // 0..127, pair {bi, bi^8} same XCD
    const int pb  = bi ^ 8;
    const int rows0 = grp * 64;

    int* prod = flags;
    int* cons = flags + 256;

    // exchange slots inside d_out: group g owns out rows [64g,64g+64) = 64KB; halves 32KB
    unsigned short* piece_me = (unsigned short*)out + (size_t)grp * 32768 + mu * 16384;
    unsigned short* piece_pa = (unsigned short*)out + (size_t)grp * 32768 + (1 - mu) * 16384;

    const float gm = gamma_p[0];
    const float g1 = gm * alphas[0], g2 = gm * alphas[1], g3 = gm * alphas[2];
    const int nsteps = steps_p[0];

    const int colbase = mu * 256 + w * 32;         // this wave's hidden cols
    const float bias0 = wxb[colbase + c] + whb[colbase + c];
    const float bias1 = wxb[colbase + 16 + c] + whb[colbase + 16 + c];
    const float hb0 = hdb[w * 32 + c], hb1 = hdb[w * 32 + 16 + c];

    const int roff = l * 8;                        // linear A-read offset (shorts)
    const int k0own = 8 * mu, k0par = 8 * (1 - mu);

    short8 bw0[16], bw1[16];

    // ================= xproj: B regs <- Wx panel (natural kt order) =================
    LOAD_PANEL(Wx_w, colbase, j);

    f32x4 acc[4][2];
    #pragma unroll
    for (int mt = 0; mt < 4; ++mt) {
        acc[mt][0] = (f32x4){0.f, 0.f, 0.f, 0.f};
        acc[mt][1] = (f32x4){0.f, 0.f, 0.f, 0.f};
    }
    #pragma unroll
    for (int pass = 0; pass < 2; ++pass) {
        __syncthreads();
        // stage 64 rows x 256 k of x as f32 A-frags into sfrag
        #pragma unroll
        for (int j2 = 0; j2 < 8; ++j2) {
            int r = j2 * 8 + w;
            int kloc = l * 4;
            float4 v = *(const float4*)(x + (size_t)(rows0 + r) * 512 + pass * 256 + kloc);
            int mtx = r >> 4, ktl = kloc >> 5;
            int lane2 = (r & 15) + 16 * ((kloc >> 3) & 3);
            float* dst = (float*)sfrag + ((mtx * 8 + ktl) * 64 + lane2) * 8 + (kloc & 7);
            *(float4*)dst = v;
        }
        __syncthreads();
        #pragma unroll
        for (int j = 0; j < 8; ++j) {
            #pragma unroll
            for (int mt = 0; mt < 4; ++mt) {
                const float* fp = (const float*)sfrag + ((mt * 8 + j) * 64 + l) * 8;
                float4 u0 = *(const float4*)fp;
                float4 u1 = *(const float4*)(fp + 4);
                short8 a = cvt8(u0, u1);
                acc[mt][0] = MFMA(a, bw0[pass * 8 + j], acc[mt][0]);
                acc[mt][1] = MFMA(a, bw1[pass * 8 + j], acc[mt][1]);
            }
        }
    }
    __syncthreads();   // xproj reads done before step-1 scatter overwrites sfrag

    // xp packed bf16 (pairs over i)
    unsigned xpk[4][2][2];
    #pragma unroll
    for (int mt = 0; mt < 4; ++mt)
        #pragma unroll
        for (int nt = 0; nt < 2; ++nt) {
            float b = nt ? bias1 : bias0;
            xpk[mt][nt][0] = pk2(acc[mt][nt][0] + b, acc[mt][nt][1] + b);
            xpk[mt][nt][1] = pk2(acc[mt][nt][2] + b, acc[mt][nt][3] + b);
        }

    // ================= B regs <- Wh panel (own-half-first kt order) =================
    LOAD_PANEL(Wh_w, colbase, (j < 8 ? k0own + j : k0par + (j - 8)));

    // zero state
    uint4 z4 = {0u, 0u, 0u, 0u};
    #pragma unroll
    for (int sb = 0; sb < 8; ++sb) *(uint4*)&hist[(sb * 512 + tid) * 4] = z4;
    float s[4][2][4];
    unsigned h0[4][2][2];
    #pragma unroll
    for (int mt = 0; mt < 4; ++mt)
        #pragma unroll
        for (int nt = 0; nt < 2; ++nt) {
            acc[mt][nt] = (f32x4){0.f, 0.f, 0.f, 0.f};
            h0[mt][nt][0] = h0[mt][nt][1] = 0u;
            #pragma unroll
            for (int i = 0; i < 4; ++i) s[mt][nt][i] = 0.f;
        }

    // ================= recurrence =================
    // iteration t: acc = s_{t-1}@Wh^T (from GEMM t-1); lags: h0 = s_{t-2},
    // hist[t&1] = s_{t-3}, hist[(t+1)&1] = s_{t-4} (round-3-verified lag structure)
    for (int t = 1; t <= nsteps; ++t) {
        const int sA = t & 1, sB = sA ^ 1;
        #pragma unroll
        for (int mt = 0; mt < 4; ++mt) {
            uint4 hA = *(uint4*)&hist[((sA * 4 + mt) * 512 + tid) * 4];
            uint4 hB = *(uint4*)&hist[((sB * 4 + mt) * 512 + tid) * 4];
            uint4 nB;
            #pragma unroll
            for (int nt = 0; nt < 2; ++nt)
                #pragma unroll
                for (int pi = 0; pi < 2; ++pi) {
                    unsigned u1 = h0[mt][nt][pi];
                    unsigned u2 = ((unsigned*)&hA)[nt * 2 + pi];
                    unsigned u3 = ((unsigned*)&hB)[nt * 2 + pi];
                    unsigned ux = xpk[mt][nt][pi];
                    float p0 = acc[mt][nt][pi * 2] + bflo(ux)
                             + g1 * bflo(u1) + g2 * bflo(u2) + g3 * bflo(u3);
                    float p1 = acc[mt][nt][pi * 2 + 1] + bfhi(ux)
                             + g1 * bfhi(u1) + g2 * bfhi(u2) + g3 * bfhi(u3);
                    float so0 = s[mt][nt][pi * 2], so1 = s[mt][nt][pi * 2 + 1];
                    float sn0 = 0.5f * so0 + 0.5f * fast_tanh(p0);
                    float sn1 = 0.5f * so1 + 0.5f * fast_tanh(p1);
                    s[mt][nt][pi * 2] = sn0; s[mt][nt][pi * 2 + 1] = sn1;
                    ((unsigned*)&nB)[nt * 2 + pi] = u1;       // s_{t-2} becomes next s_{t-4} slot
                    h0[mt][nt][pi] = pk2(so0, so1);           // s_{t-1} for next iteration
                }
            *(uint4*)&hist[((sB * 4 + mt) * 512 + tid) * 4] = nB;
            acc[mt][0] = (f32x4){0.f, 0.f, 0.f, 0.f};
            acc[mt][1] = (f32x4){0.f, 0.f, 0.f, 0.f};
        }

        // partner must have consumed our piece of step t-1 before we overwrite it
        if (l == 0) { while (ldf(&cons[pb]) < t - 1) __builtin_amdgcn_s_sleep(1); }
        __builtin_amdgcn_sched_barrier(0);

        // scatter s_t into own LDS rows (kt = k0own + w per wave)
        #pragma unroll
        for (int mt = 0; mt < 4; ++mt)
            #pragma unroll
            for (int nt = 0; nt < 2; ++nt)
                #pragma unroll
                for (int i = 0; i < 4; ++i) {
                    int lam = q * 4 + i + 16 * (nt * 2 + (c >> 3));
                    sfrag[(mt * 16 + k0own + w) * 512 + lam * 8 + (c & 7)] = f2bf(s[mt][nt][i]);
                }
        __syncthreads();

        // coalesced copy own LDS region -> piece_me (16B/lane linear)
        #pragma unroll
        for (int j2 = 0; j2 < 4; ++j2) {
            int u = j2 * 512 + tid;                   // 16B unit, [0,2048)
            int mtg = u >> 9, ktl = (u >> 6) & 7, co = (u & 63) * 8;
            uint4 v = *(const uint4*)&sfrag[(mtg * 16 + k0own + ktl) * 512 + co];
            *(uint4*)&piece_me[(size_t)u * 8] = v;
        }

        if (t == nsteps) {
            WAITV0();
            __builtin_amdgcn_s_barrier();
            if (tid == 0) stf(&prod[bi], t);
            break;
        }

        // own-half GEMM (kt = k0own + j) hides the piece-store drain
        #pragma unroll
        for (int j = 0; j < 8; ++j) {
            const int kt = k0own + j;
            short8 a0 = *(const short8*)&sfrag[(0 * 16 + kt) * 512 + roff];
            short8 a1 = *(const short8*)&sfrag[(1 * 16 + kt) * 512 + roff];
            short8 a2 = *(const short8*)&sfrag[(2 * 16 + kt) * 512 + roff];
            short8 a3 = *(const short8*)&sfrag[(3 * 16 + kt) * 512 + roff];
            acc[0][0] = MFMA(a0, bw0[j], acc[0][0]); acc[0][1] = MFMA(a0, bw1[j], acc[0][1]);
            acc[1][0] = MFMA(a1, bw0[j], acc[1][0]); acc[1][1] = MFMA(a1, bw1[j], acc[1][1]);
            acc[2][0] = MFMA(a2, bw0[j], acc[2][0]); acc[2][1] = MFMA(a2, bw1[j], acc[2][1]);
            acc[3][0] = MFMA(a3, bw0[j], acc[3][0]); acc[3][1] = MFMA(a3, bw1[j], acc[3][1]);
        }

        WAITV0();                                     // piece stores complete (in L2)
        __builtin_amdgcn_s_barrier();
        if (tid == 0) stf(&prod[bi], t);

        // partner piece ready? stage it (linear gl_lds)
        if (l == 0) { while (ldf(&prod[pb]) < t) __builtin_amdgcn_s_sleep(1); }
        __builtin_amdgcn_sched_barrier(0);
        {
            const int mtg = w >> 1;
            #pragma unroll
            for (int i2 = 0; i2 < 4; ++i2) {
                const int ktl = 4 * (w & 1) + i2;
                gl_lds16(piece_pa + (mtg * 8 + ktl) * 512 + l * 8,
                         &sfrag[(mtg * 16 + k0par + ktl) * 512]);
            }
        }
        __syncthreads();                              // drains gl_lds vmcnt + barrier
        if (tid == 0) stf(&cons[bi], t);

        // partner-half GEMM (kt = k0par + (j-8))
        #pragma unroll
        for (int j = 8; j < 16; ++j) {
            const int kt = k0par + (j - 8);
            short8 a0 = *(const short8*)&sfrag[(0 * 16 + kt) * 512 + roff];
            short8 a1 = *(const short8*)&sfrag[(1 * 16 + kt) * 512 + roff];
            short8 a2 = *(const short8*)&sfrag[(2 * 16 + kt) * 512 + roff];
            short8 a3 = *(const short8*)&sfrag[(3 * 16 + kt) * 512 + roff];
            acc[0][0] = MFMA(a0, bw0[j], acc[0][0]); acc[0][1] = MFMA(a0, bw1[j], acc[0][1]);
            acc[1][0] = MFMA(a1, bw0[j], acc[1][0]); acc[1][1] = MFMA(a1, bw1[j], acc[1][1]);
            acc[2][0] = MFMA(a2, bw0[j], acc[2][0]); acc[2][1] = MFMA(a2, bw1[j], acc[2][1]);
            acc[3][0] = MFMA(a3, bw0[j], acc[3][0]); acc[3][1] = MFMA(a3, bw1[j], acc[3][1]);
        }
    }

    // ================= head: out = s_final @ Head^T + Head_b =================
    if (l == 0) { while (ldf(&prod[pb]) < nsteps) __builtin_amdgcn_s_sleep(1); }
    __builtin_amdgcn_sched_barrier(0);
    {
        const int mtg = w >> 1;
        #pragma unroll
        for (int i2 = 0; i2 < 4; ++i2) {
            const int ktl = 4 * (w & 1) + i2;
            gl_lds16(piece_pa + (mtg * 8 + ktl) * 512 + l * 8,
                     &sfrag[(mtg * 16 + k0par + ktl) * 512]);
        }
    }
    // B regs <- Head panel (own-first kt order; wave w covers out cols [32w,32w+32))
    LOAD_PANEL(Hd_w, w * 32, (j < 8 ? k0own + j : k0par + (j - 8)));
    __syncthreads();
    if (tid == 0) stf(&cons[bi], nsteps);

    f32x4 ah[2][2];
    ah[0][0] = (f32x4){0.f, 0.f, 0.f, 0.f}; ah[0][1] = (f32x4){0.f, 0.f, 0.f, 0.f};
    ah[1][0] = (f32x4){0.f, 0.f, 0.f, 0.f}; ah[1][1] = (f32x4){0.f, 0.f, 0.f, 0.f};
    #pragma unroll
    for (int j = 0; j < 16; ++j) {
        const int kt = (j < 8) ? k0own + j : k0par + (j - 8);
        short8 a0 = *(const short8*)&sfrag[((2 * mu + 0) * 16 + kt) * 512 + roff];
        short8 a1 = *(const short8*)&sfrag[((2 * mu + 1) * 16 + kt) * 512 + roff];
        ah[0][0] = MFMA(a0, bw0[j], ah[0][0]); ah[0][1] = MFMA(a0, bw1[j], ah[0][1]);
        ah[1][0] = MFMA(a1, bw0[j], ah[1][0]); ah[1][1] = MFMA(a1, bw1[j], ah[1][1]);
    }

    // partner must be done reading our piece before final output overwrites it
    if (l == 0) { while (ldf(&cons[pb]) < nsteps) __builtin_amdgcn_s_sleep(1); }
    __builtin_amdgcn_sched_barrier(0);
    #pragma unroll
    for (int mtL = 0; mtL < 2; ++mtL)
        #pragma unroll
        for (int i = 0; i < 4; ++i) {
            int r = rows0 + 32 * mu + mtL * 16 + q * 4 + i;
            out[(size_t)r * 256 + w * 32 + c]      = ah[mtL][0][i] + hb0;
            out[(size_t)r * 256 + w * 32 + 16 + c] = ah[mtL][1][i] + hb1;
        }
}

extern "C" void kernel_launch(void* const* d_in, const int* in_sizes, int n_in,
                              void* d_out, int out_size, void* d_ws, size_t ws_size,
                              hipStream_t stream) {
    (void)n_in; (void)out_size;
    const float* x    = (const float*)d_in[0];
    const float* Wx_w = (const float*)d_in[1];
    const float* Wx_b = (const float*)d_in[2];
    const float* Wh_w = (const float*)d_in[3];
    const float* Wh_b = (const float*)d_in[4];
    const float* Hd_w = (const float*)d_in[5];
    const float* Hd_b = (const float*)d_in[6];
    const float* gma  = (const float*)d_in[7];
    const float* alp  = (const float*)d_in[8];
    const int*   stp  = (const int*)d_in[9];
    float* out = (float*)d_out;

    if (ws_size < 4096) return;
    int* flags = (int*)d_ws;
    hipMemsetAsync(flags, 0, 4096, stream);    // prod[256] + cons[256], reset every launch

    int batch = in_sizes[0] / 512;             // 8192
    int nblk  = batch / 32;                    // 256 blocks = 128 pairs
    toroidal<<<nblk, THREADS, 0, stream>>>(x, Wx_w, Wx_b, Wh_w, Wh_b, Hd_w, Hd_b,
                                           gma, alp, stp, out, flags);
}

// Round 5
// 643.158 us; speedup vs baseline: 3.0161x; 2.7790x over previous
//
#include <hip/hip_runtime.h>
#include <hip/hip_bf16.h>

typedef __attribute__((ext_vector_type(8))) short short8;
typedef __attribute__((ext_vector_type(4))) float f32x4;

#define THREADS 512
#define MFMA(a, b, c) __builtin_amdgcn_mfma_f32_16x16x32_bf16((a), (b), (c), 0, 0, 0)

static __device__ __forceinline__ unsigned short f2bf(float x) {
    __hip_bfloat16 h = __float2bfloat16(x);
    return __builtin_bit_cast(unsigned short, h);
}
static __device__ __forceinline__ unsigned pk2(float a, float b) {
    return (unsigned)f2bf(a) | ((unsigned)f2bf(b) << 16);
}
static __device__ __forceinline__ float bflo(unsigned u) {
    unsigned v = u << 16; return __builtin_bit_cast(float, v);
}
static __device__ __forceinline__ float bfhi(unsigned u) {
    unsigned v = u & 0xffff0000u; return __builtin_bit_cast(float, v);
}
static __device__ __forceinline__ float fast_tanh(float x) {
    float e = __builtin_amdgcn_exp2f(x * 2.885390081777927f);
    float r = __builtin_amdgcn_rcpf(e + 1.0f);
    return fmaf(-2.0f, r, 1.0f);
}
static __device__ __forceinline__ short8 cvt8(float4 a, float4 b) {
    short8 r;
    r[0] = (short)f2bf(a.x); r[1] = (short)f2bf(a.y);
    r[2] = (short)f2bf(a.z); r[3] = (short)f2bf(a.w);
    r[4] = (short)f2bf(b.x); r[5] = (short)f2bf(b.y);
    r[6] = (short)f2bf(b.z); r[7] = (short)f2bf(b.w);
    return r;
}
// async global -> LDS, 16B/lane, sc0=1 (bypass CU L1; pair partner shares our XCD L2)
static __device__ __forceinline__ void gl_lds16(const unsigned short* g, unsigned short* l) {
    __builtin_amdgcn_global_load_lds(
        (const __attribute__((address_space(1))) unsigned int*)g,
        (__attribute__((address_space(3))) unsigned int*)l, 16, 0, 1);
}
// RELAXED atomics: no buffer_inv / buffer_wb. Same-XCD L2 provides the ordering:
// producer: piece stores -> vmcnt(0) (L2-ack'd) -> flag store (same L2).
static __device__ __forceinline__ int ldf(int* p) {
    return __hip_atomic_load(p, __ATOMIC_RELAXED, __HIP_MEMORY_SCOPE_AGENT);
}
static __device__ __forceinline__ void stf(int* p, int v) {
    __hip_atomic_store(p, v, __ATOMIC_RELAXED, __HIP_MEMORY_SCOPE_AGENT);
}
#define WAITV0() asm volatile("s_waitcnt vmcnt(0)" ::: "memory")

// Load a 32-col x 512-k bf16 B-panel into registers.
// B-frag (16x16x32, round-1-verified): lane holds W[colbase + nt*16 + (l&15)][kt*32 + (l>>4)*8 + e]
#define LOAD_PANEL(W, CB, KT_OF_J)                                              \
    do {                                                                        \
        _Pragma("unroll")                                                       \
        for (int j = 0; j < 16; ++j) {                                          \
            const int kt_ = (KT_OF_J);                                          \
            const float* p0_ = (W) + (size_t)((CB) + c) * 512 + kt_ * 32 + q * 8;       \
            const float* p1_ = (W) + (size_t)((CB) + 16 + c) * 512 + kt_ * 32 + q * 8;  \
            float4 a0_ = *(const float4*)p0_, b0_ = *(const float4*)(p0_ + 4);  \
            float4 a1_ = *(const float4*)p1_, b1_ = *(const float4*)(p1_ + 4);  \
            bw0[j] = cvt8(a0_, b0_);                                            \
            bw1[j] = cvt8(a1_, b1_);                                            \
        }                                                                       \
    } while (0)

__global__ __attribute__((amdgpu_flat_work_group_size(512, 512), amdgpu_waves_per_eu(2, 2)))
void toroidal(
    const float* __restrict__ x,
    const float* __restrict__ Wx_w, const float* __restrict__ wxb,
    const float* __restrict__ Wh_w, const float* __restrict__ whb,
    const float* __restrict__ Hd_w, const float* __restrict__ hdb,
    const float* __restrict__ gamma_p, const float* __restrict__ alphas,
    const int* __restrict__ steps_p,
    float* __restrict__ out, int* __restrict__ flags)
{
    __shared__ __align__(16) unsigned short sfrag[32768];  // 64KB: A-frags [mt4][kt16][lane64][e8]
    __shared__ __align__(16) unsigned int   hist[16384];   // 64KB: 2 slots x 4 mt x 512 tid x 4 u32

    const int tid = threadIdx.x;
    const int w = tid >> 6;
    const int l = tid & 63;
    const int q = l >> 4;
    const int c = l & 15;

    const int bi  = blockIdx.x;
    const int mu  = (bi >> 3) & 1;                 // pair member
    const int grp = (bi & 7) * 16 + (bi >> 4);     // 0..127, pair {bi, bi^8} same XCD
    const int pb  = bi ^ 8;
    const int rows0 = grp * 64;

    int* prod = flags;
    int* cons = flags + 256;

    // exchange slots inside d_out: group g owns out rows [64g,64g+64) = 64KB; halves 32KB
    unsigned short* piece_me = (unsigned short*)out + (size_t)grp * 32768 + mu * 16384;
    unsigned short* piece_pa = (unsigned short*)out + (size_t)grp * 32768 + (1 - mu) * 16384;

    const float gm = gamma_p[0];
    const float g1 = gm * alphas[0], g2 = gm * alphas[1], g3 = gm * alphas[2];
    const int nsteps = steps_p[0];

    const int colbase = mu * 256 + w * 32;         // this wave's hidden cols
    const float bias0 = wxb[colbase + c] + whb[colbase + c];
    const float bias1 = wxb[colbase + 16 + c] + whb[colbase + 16 + c];
    const float hb0 = hdb[w * 32 + c], hb1 = hdb[w * 32 + 16 + c];

    const int roff = l * 8;                        // linear A-read offset (shorts)
    const int k0own = 8 * mu, k0par = 8 * (1 - mu);

    short8 bw0[16], bw1[16];

    // ================= xproj: B regs <- Wx panel (natural kt order) =================
    LOAD_PANEL(Wx_w, colbase, j);

    f32x4 acc[4][2];
    #pragma unroll
    for (int mt = 0; mt < 4; ++mt) {
        acc[mt][0] = (f32x4){0.f, 0.f, 0.f, 0.f};
        acc[mt][1] = (f32x4){0.f, 0.f, 0.f, 0.f};
    }
    #pragma unroll
    for (int pass = 0; pass < 2; ++pass) {
        __syncthreads();
        // stage 64 rows x 256 k of x as f32 A-frags into sfrag
        #pragma unroll
        for (int j2 = 0; j2 < 8; ++j2) {
            int r = j2 * 8 + w;
            int kloc = l * 4;
            float4 v = *(const float4*)(x + (size_t)(rows0 + r) * 512 + pass * 256 + kloc);
            int mtx = r >> 4, ktl = kloc >> 5;
            int lane2 = (r & 15) + 16 * ((kloc >> 3) & 3);
            float* dst = (float*)sfrag + ((mtx * 8 + ktl) * 64 + lane2) * 8 + (kloc & 7);
            *(float4*)dst = v;
        }
        __syncthreads();
        #pragma unroll
        for (int j = 0; j < 8; ++j) {
            #pragma unroll
            for (int mt = 0; mt < 4; ++mt) {
                const float* fp = (const float*)sfrag + ((mt * 8 + j) * 64 + l) * 8;
                float4 u0 = *(const float4*)fp;
                float4 u1 = *(const float4*)(fp + 4);
                short8 a = cvt8(u0, u1);
                acc[mt][0] = MFMA(a, bw0[pass * 8 + j], acc[mt][0]);
                acc[mt][1] = MFMA(a, bw1[pass * 8 + j], acc[mt][1]);
            }
        }
    }
    __syncthreads();   // xproj reads done before step-1 scatter overwrites sfrag

    // xp packed bf16 (pairs over i)
    unsigned xpk[4][2][2];
    #pragma unroll
    for (int mt = 0; mt < 4; ++mt)
        #pragma unroll
        for (int nt = 0; nt < 2; ++nt) {
            float b = nt ? bias1 : bias0;
            xpk[mt][nt][0] = pk2(acc[mt][nt][0] + b, acc[mt][nt][1] + b);
            xpk[mt][nt][1] = pk2(acc[mt][nt][2] + b, acc[mt][nt][3] + b);
        }

    // ================= B regs <- Wh panel (own-half-first kt order) =================
    LOAD_PANEL(Wh_w, colbase, (j < 8 ? k0own + j : k0par + (j - 8)));

    // zero state
    uint4 z4 = {0u, 0u, 0u, 0u};
    #pragma unroll
    for (int sb = 0; sb < 8; ++sb) *(uint4*)&hist[(sb * 512 + tid) * 4] = z4;
    float s[4][2][4];
    unsigned h0[4][2][2];
    #pragma unroll
    for (int mt = 0; mt < 4; ++mt)
        #pragma unroll
        for (int nt = 0; nt < 2; ++nt) {
            acc[mt][nt] = (f32x4){0.f, 0.f, 0.f, 0.f};
            h0[mt][nt][0] = h0[mt][nt][1] = 0u;
            #pragma unroll
            for (int i = 0; i < 4; ++i) s[mt][nt][i] = 0.f;
        }

    // ================= recurrence =================
    // iteration t: acc = s_{t-1}@Wh^T (from GEMM t-1); lags: h0 = s_{t-2},
    // hist[t&1] = s_{t-3}, hist[(t+1)&1] = s_{t-4} (round-3-verified lag structure)
    for (int t = 1; t <= nsteps; ++t) {
        const int sA = t & 1, sB = sA ^ 1;
        #pragma unroll
        for (int mt = 0; mt < 4; ++mt) {
            uint4 hA = *(uint4*)&hist[((sA * 4 + mt) * 512 + tid) * 4];
            uint4 hB = *(uint4*)&hist[((sB * 4 + mt) * 512 + tid) * 4];
            uint4 nB;
            #pragma unroll
            for (int nt = 0; nt < 2; ++nt)
                #pragma unroll
                for (int pi = 0; pi < 2; ++pi) {
                    unsigned u1 = h0[mt][nt][pi];
                    unsigned u2 = ((unsigned*)&hA)[nt * 2 + pi];
                    unsigned u3 = ((unsigned*)&hB)[nt * 2 + pi];
                    unsigned ux = xpk[mt][nt][pi];
                    float p0 = acc[mt][nt][pi * 2] + bflo(ux)
                             + g1 * bflo(u1) + g2 * bflo(u2) + g3 * bflo(u3);
                    float p1 = acc[mt][nt][pi * 2 + 1] + bfhi(ux)
                             + g1 * bfhi(u1) + g2 * bfhi(u2) + g3 * bfhi(u3);
                    float so0 = s[mt][nt][pi * 2], so1 = s[mt][nt][pi * 2 + 1];
                    float sn0 = 0.5f * so0 + 0.5f * fast_tanh(p0);
                    float sn1 = 0.5f * so1 + 0.5f * fast_tanh(p1);
                    s[mt][nt][pi * 2] = sn0; s[mt][nt][pi * 2 + 1] = sn1;
                    ((unsigned*)&nB)[nt * 2 + pi] = u1;       // s_{t-2} becomes next s_{t-4} slot
                    h0[mt][nt][pi] = pk2(so0, so1);           // s_{t-1} for next iteration
                }
            *(uint4*)&hist[((sB * 4 + mt) * 512 + tid) * 4] = nB;
            acc[mt][0] = (f32x4){0.f, 0.f, 0.f, 0.f};
            acc[mt][1] = (f32x4){0.f, 0.f, 0.f, 0.f};
        }

        // partner must have consumed our piece of step t-1 before we overwrite it
        if (l == 0) { while (ldf(&cons[pb]) < t - 1) __builtin_amdgcn_s_sleep(1); }
        __builtin_amdgcn_sched_barrier(0);

        // scatter s_t into own LDS rows (kt = k0own + w per wave)
        #pragma unroll
        for (int mt = 0; mt < 4; ++mt)
            #pragma unroll
            for (int nt = 0; nt < 2; ++nt)
                #pragma unroll
                for (int i = 0; i < 4; ++i) {
                    int lam = q * 4 + i + 16 * (nt * 2 + (c >> 3));
                    sfrag[(mt * 16 + k0own + w) * 512 + lam * 8 + (c & 7)] = f2bf(s[mt][nt][i]);
                }
        __syncthreads();

        // coalesced copy own LDS region -> piece_me (16B/lane linear)
        #pragma unroll
        for (int j2 = 0; j2 < 4; ++j2) {
            int u = j2 * 512 + tid;                   // 16B unit, [0,2048)
            int mtg = u >> 9, ktl = (u >> 6) & 7, co = (u & 63) * 8;
            uint4 v = *(const uint4*)&sfrag[(mtg * 16 + k0own + ktl) * 512 + co];
            *(uint4*)&piece_me[(size_t)u * 8] = v;
        }

        if (t == nsteps) {
            WAITV0();
            __builtin_amdgcn_s_barrier();
            if (tid == 0) stf(&prod[bi], t);
            break;
        }

        // own-half GEMM (kt = k0own + j) hides the piece-store drain
        #pragma unroll
        for (int j = 0; j < 8; ++j) {
            const int kt = k0own + j;
            short8 a0 = *(const short8*)&sfrag[(0 * 16 + kt) * 512 + roff];
            short8 a1 = *(const short8*)&sfrag[(1 * 16 + kt) * 512 + roff];
            short8 a2 = *(const short8*)&sfrag[(2 * 16 + kt) * 512 + roff];
            short8 a3 = *(const short8*)&sfrag[(3 * 16 + kt) * 512 + roff];
            acc[0][0] = MFMA(a0, bw0[j], acc[0][0]); acc[0][1] = MFMA(a0, bw1[j], acc[0][1]);
            acc[1][0] = MFMA(a1, bw0[j], acc[1][0]); acc[1][1] = MFMA(a1, bw1[j], acc[1][1]);
            acc[2][0] = MFMA(a2, bw0[j], acc[2][0]); acc[2][1] = MFMA(a2, bw1[j], acc[2][1]);
            acc[3][0] = MFMA(a3, bw0[j], acc[3][0]); acc[3][1] = MFMA(a3, bw1[j], acc[3][1]);
        }

        WAITV0();                                     // piece stores L2-ack'd
        __builtin_amdgcn_s_barrier();
        if (tid == 0) stf(&prod[bi], t);

        // partner piece ready? stage it (linear gl_lds)
        if (l == 0) { while (ldf(&prod[pb]) < t) __builtin_amdgcn_s_sleep(1); }
        __builtin_amdgcn_sched_barrier(0);
        {
            const int mtg = w >> 1;
            #pragma unroll
            for (int i2 = 0; i2 < 4; ++i2) {
                const int ktl = 4 * (w & 1) + i2;
                gl_lds16(piece_pa + (mtg * 8 + ktl) * 512 + l * 8,
                         &sfrag[(mtg * 16 + k0par + ktl) * 512]);
            }
        }
        __syncthreads();                              // drains gl_lds vmcnt + barrier
        if (tid == 0) stf(&cons[bi], t);

        // partner-half GEMM (kt = k0par + (j-8))
        #pragma unroll
        for (int j = 8; j < 16; ++j) {
            const int kt = k0par + (j - 8);
            short8 a0 = *(const short8*)&sfrag[(0 * 16 + kt) * 512 + roff];
            short8 a1 = *(const short8*)&sfrag[(1 * 16 + kt) * 512 + roff];
            short8 a2 = *(const short8*)&sfrag[(2 * 16 + kt) * 512 + roff];
            short8 a3 = *(const short8*)&sfrag[(3 * 16 + kt) * 512 + roff];
            acc[0][0] = MFMA(a0, bw0[j], acc[0][0]); acc[0][1] = MFMA(a0, bw1[j], acc[0][1]);
            acc[1][0] = MFMA(a1, bw0[j], acc[1][0]); acc[1][1] = MFMA(a1, bw1[j], acc[1][1]);
            acc[2][0] = MFMA(a2, bw0[j], acc[2][0]); acc[2][1] = MFMA(a2, bw1[j], acc[2][1]);
            acc[3][0] = MFMA(a3, bw0[j], acc[3][0]); acc[3][1] = MFMA(a3, bw1[j], acc[3][1]);
        }
    }

    // ================= head: out = s_final @ Head^T + Head_b =================
    if (l == 0) { while (ldf(&prod[pb]) < nsteps) __builtin_amdgcn_s_sleep(1); }
    __builtin_amdgcn_sched_barrier(0);
    {
        const int mtg = w >> 1;
        #pragma unroll
        for (int i2 = 0; i2 < 4; ++i2) {
            const int ktl = 4 * (w & 1) + i2;
            gl_lds16(piece_pa + (mtg * 8 + ktl) * 512 + l * 8,
                     &sfrag[(mtg * 16 + k0par + ktl) * 512]);
        }
    }
    // B regs <- Head panel (own-first kt order; wave w covers out cols [32w,32w+32))
    LOAD_PANEL(Hd_w, w * 32, (j < 8 ? k0own + j : k0par + (j - 8)));
    __syncthreads();
    if (tid == 0) stf(&cons[bi], nsteps);

    f32x4 ah[2][2];
    ah[0][0] = (f32x4){0.f, 0.f, 0.f, 0.f}; ah[0][1] = (f32x4){0.f, 0.f, 0.f, 0.f};
    ah[1][0] = (f32x4){0.f, 0.f, 0.f, 0.f}; ah[1][1] = (f32x4){0.f, 0.f, 0.f, 0.f};
    #pragma unroll
    for (int j = 0; j < 16; ++j) {
        const int kt = (j < 8) ? k0own + j : k0par + (j - 8);
        short8 a0 = *(const short8*)&sfrag[((2 * mu + 0) * 16 + kt) * 512 + roff];
        short8 a1 = *(const short8*)&sfrag[((2 * mu + 1) * 16 + kt) * 512 + roff];
        ah[0][0] = MFMA(a0, bw0[j], ah[0][0]); ah[0][1] = MFMA(a0, bw1[j], ah[0][1]);
        ah[1][0] = MFMA(a1, bw0[j], ah[1][0]); ah[1][1] = MFMA(a1, bw1[j], ah[1][1]);
    }

    // partner must be done reading our piece before final output overwrites it
    if (l == 0) { while (ldf(&cons[pb]) < nsteps) __builtin_amdgcn_s_sleep(1); }
    __builtin_amdgcn_sched_barrier(0);
    #pragma unroll
    for (int mtL = 0; mtL < 2; ++mtL)
        #pragma unroll
        for (int i = 0; i < 4; ++i) {
            int r = rows0 + 32 * mu + mtL * 16 + q * 4 + i;
            out[(size_t)r * 256 + w * 32 + c]      = ah[mtL][0][i] + hb0;
            out[(size_t)r * 256 + w * 32 + 16 + c] = ah[mtL][1][i] + hb1;
        }
}

extern "C" void kernel_launch(void* const* d_in, const int* in_sizes, int n_in,
                              void* d_out, int out_size, void* d_ws, size_t ws_size,
                              hipStream_t stream) {
    (void)n_in; (void)out_size;
    const float* x    = (const float*)d_in[0];
    const float* Wx_w = (const float*)d_in[1];
    const float* Wx_b = (const float*)d_in[2];
    const float* Wh_w = (const float*)d_in[3];
    const float* Wh_b = (const float*)d_in[4];
    const float* Hd_w = (const float*)d_in[5];
    const float* Hd_b = (const float*)d_in[6];
    const float* gma  = (const float*)d_in[7];
    const float* alp  = (const float*)d_in[8];
    const int*   stp  = (const int*)d_in[9];
    float* out = (float*)d_out;

    if (ws_size < 4096) return;
    int* flags = (int*)d_ws;
    hipMemsetAsync(flags, 0, 4096, stream);    // prod[256] + cons[256], reset every launch

    int batch = in_sizes[0] / 512;             // 8192
    int nblk  = batch / 32;                    // 256 blocks = 128 pairs
    toroidal<<<nblk, THREADS, 0, stream>>>(x, Wx_w, Wx_b, Wh_w, Wh_b, Hd_w, Hd_b,
                                           gma, alp, stp, out, flags);
}

// Round 6
// 642.999 us; speedup vs baseline: 3.0168x; 1.0002x over previous
//
#include <hip/hip_runtime.h>
#include <hip/hip_bf16.h>

typedef __attribute__((ext_vector_type(8))) short short8;
typedef __attribute__((ext_vector_type(4))) float f32x4;

#define THREADS 512
#define MFMA(a, b, c) __builtin_amdgcn_mfma_f32_16x16x32_bf16((a), (b), (c), 0, 0, 0)

static __device__ __forceinline__ unsigned short f2bf(float x) {
    __hip_bfloat16 h = __float2bfloat16(x);
    return __builtin_bit_cast(unsigned short, h);
}
static __device__ __forceinline__ unsigned pk2(float a, float b) {
    return (unsigned)f2bf(a) | ((unsigned)f2bf(b) << 16);
}
static __device__ __forceinline__ float bflo(unsigned u) {
    unsigned v = u << 16; return __builtin_bit_cast(float, v);
}
static __device__ __forceinline__ float bfhi(unsigned u) {
    unsigned v = u & 0xffff0000u; return __builtin_bit_cast(float, v);
}
static __device__ __forceinline__ float fast_tanh(float x) {
    float e = __builtin_amdgcn_exp2f(x * 2.885390081777927f);
    float r = __builtin_amdgcn_rcpf(e + 1.0f);
    return fmaf(-2.0f, r, 1.0f);
}
static __device__ __forceinline__ short8 cvt8(float4 a, float4 b) {
    short8 r;
    r[0] = (short)f2bf(a.x); r[1] = (short)f2bf(a.y);
    r[2] = (short)f2bf(a.z); r[3] = (short)f2bf(a.w);
    r[4] = (short)f2bf(b.x); r[5] = (short)f2bf(b.y);
    r[6] = (short)f2bf(b.z); r[7] = (short)f2bf(b.w);
    return r;
}
// async global -> LDS, 16B/lane, sc0=1 (bypass CU L1; pair partner shares our XCD L2)
static __device__ __forceinline__ void gl_lds16(const unsigned short* g, unsigned short* l) {
    __builtin_amdgcn_global_load_lds(
        (const __attribute__((address_space(1))) unsigned int*)g,
        (__attribute__((address_space(3))) unsigned int*)l, 16, 0, 1);
}
// RELAXED atomics: no buffer_inv / buffer_wb. Same-XCD L2 provides the ordering:
// producer: piece stores -> vmcnt(0) (L2-ack'd) -> flag store (same L2).
static __device__ __forceinline__ int ldf(int* p) {
    return __hip_atomic_load(p, __ATOMIC_RELAXED, __HIP_MEMORY_SCOPE_AGENT);
}
static __device__ __forceinline__ void stf(int* p, int v) {
    __hip_atomic_store(p, v, __ATOMIC_RELAXED, __HIP_MEMORY_SCOPE_AGENT);
}
#define WAITV0() asm volatile("s_waitcnt vmcnt(0)" ::: "memory")

// Load a 32-col x 512-k bf16 B-panel into registers.
// B-frag (16x16x32, round-1-verified): lane holds W[colbase + nt*16 + (l&15)][kt*32 + (l>>4)*8 + e]
#define LOAD_PANEL(W, CB, KT_OF_J)                                              \
    do {                                                                        \
        _Pragma("unroll")                                                       \
        for (int j = 0; j < 16; ++j) {                                          \
            const int kt_ = (KT_OF_J);                                          \
            const float* p0_ = (W) + (size_t)((CB) + c) * 512 + kt_ * 32 + q * 8;       \
            const float* p1_ = (W) + (size_t)((CB) + 16 + c) * 512 + kt_ * 32 + q * 8;  \
            float4 a0_ = *(const float4*)p0_, b0_ = *(const float4*)(p0_ + 4);  \
            float4 a1_ = *(const float4*)p1_, b1_ = *(const float4*)(p1_ + 4);  \
            bw0[j] = cvt8(a0_, b0_);                                            \
            bw1[j] = cvt8(a1_, b1_);                                            \
        }                                                                       \
    } while (0)

__global__ __attribute__((amdgpu_flat_work_group_size(512, 512), amdgpu_waves_per_eu(2, 2)))
void toroidal(
    const float* __restrict__ x,
    const float* __restrict__ Wx_w, const float* __restrict__ wxb,
    const float* __restrict__ Wh_w, const float* __restrict__ whb,
    const float* __restrict__ Hd_w, const float* __restrict__ hdb,
    const float* __restrict__ gamma_p, const float* __restrict__ alphas,
    const int* __restrict__ steps_p,
    float* __restrict__ out, int* __restrict__ flags,
    unsigned short* __restrict__ pieces)
{
    __shared__ __align__(16) unsigned short sfrag[32768];  // 64KB: A-frags [mt4][kt16][lane64][e8]
    __shared__ __align__(16) unsigned int   hist[16384];   // 64KB: 2 slots x 4 mt x 512 tid x 4 u32

    const int tid = threadIdx.x;
    const int w = tid >> 6;
    const int l = tid & 63;
    const int q = l >> 4;
    const int c = l & 15;

    const int bi  = blockIdx.x;
    const int mu  = (bi >> 3) & 1;                 // pair member
    const int grp = (bi & 7) * 16 + (bi >> 4);     // 0..127, pair {bi, bi^8} same XCD
    const int pb  = bi ^ 8;
    const int rows0 = grp * 64;

    int* prod = flags;
    int* cons = flags + 256;

    // exchange slots in d_ws (coarse-grained, L2-cacheable): group g = 64KB, member halves 32KB
    unsigned short* piece_me = pieces + (size_t)grp * 32768 + mu * 16384;
    unsigned short* piece_pa = pieces + (size_t)grp * 32768 + (1 - mu) * 16384;

    const float gm = gamma_p[0];
    const float g1 = gm * alphas[0], g2 = gm * alphas[1], g3 = gm * alphas[2];
    const int nsteps = steps_p[0];

    const int colbase = mu * 256 + w * 32;         // this wave's hidden cols
    const float bias0 = wxb[colbase + c] + whb[colbase + c];
    const float bias1 = wxb[colbase + 16 + c] + whb[colbase + 16 + c];
    const float hb0 = hdb[w * 32 + c], hb1 = hdb[w * 32 + 16 + c];

    const int roff = l * 8;                        // linear A-read offset (shorts)
    const int k0own = 8 * mu, k0par = 8 * (1 - mu);

    short8 bw0[16], bw1[16];

    // ================= xproj: B regs <- Wx panel (natural kt order) =================
    LOAD_PANEL(Wx_w, colbase, j);

    f32x4 acc[4][2];
    #pragma unroll
    for (int mt = 0; mt < 4; ++mt) {
        acc[mt][0] = (f32x4){0.f, 0.f, 0.f, 0.f};
        acc[mt][1] = (f32x4){0.f, 0.f, 0.f, 0.f};
    }
    #pragma unroll
    for (int pass = 0; pass < 2; ++pass) {
        __syncthreads();
        // stage 64 rows x 256 k of x as f32 A-frags into sfrag
        #pragma unroll
        for (int j2 = 0; j2 < 8; ++j2) {
            int r = j2 * 8 + w;
            int kloc = l * 4;
            float4 v = *(const float4*)(x + (size_t)(rows0 + r) * 512 + pass * 256 + kloc);
            int mtx = r >> 4, ktl = kloc >> 5;
            int lane2 = (r & 15) + 16 * ((kloc >> 3) & 3);
            float* dst = (float*)sfrag + ((mtx * 8 + ktl) * 64 + lane2) * 8 + (kloc & 7);
            *(float4*)dst = v;
        }
        __syncthreads();
        #pragma unroll
        for (int j = 0; j < 8; ++j) {
            #pragma unroll
            for (int mt = 0; mt < 4; ++mt) {
                const float* fp = (const float*)sfrag + ((mt * 8 + j) * 64 + l) * 8;
                float4 u0 = *(const float4*)fp;
                float4 u1 = *(const float4*)(fp + 4);
                short8 a = cvt8(u0, u1);
                acc[mt][0] = MFMA(a, bw0[pass * 8 + j], acc[mt][0]);
                acc[mt][1] = MFMA(a, bw1[pass * 8 + j], acc[mt][1]);
            }
        }
    }
    __syncthreads();   // xproj reads done before step-1 scatter overwrites sfrag

    // xp packed bf16 (pairs over i)
    unsigned xpk[4][2][2];
    #pragma unroll
    for (int mt = 0; mt < 4; ++mt)
        #pragma unroll
        for (int nt = 0; nt < 2; ++nt) {
            float b = nt ? bias1 : bias0;
            xpk[mt][nt][0] = pk2(acc[mt][nt][0] + b, acc[mt][nt][1] + b);
            xpk[mt][nt][1] = pk2(acc[mt][nt][2] + b, acc[mt][nt][3] + b);
        }

    // ================= B regs <- Wh panel (own-half-first kt order) =================
    LOAD_PANEL(Wh_w, colbase, (j < 8 ? k0own + j : k0par + (j - 8)));

    // zero state
    uint4 z4 = {0u, 0u, 0u, 0u};
    #pragma unroll
    for (int sb = 0; sb < 8; ++sb) *(uint4*)&hist[(sb * 512 + tid) * 4] = z4;
    float s[4][2][4];
    unsigned h0[4][2][2];
    #pragma unroll
    for (int mt = 0; mt < 4; ++mt)
        #pragma unroll
        for (int nt = 0; nt < 2; ++nt) {
            acc[mt][nt] = (f32x4){0.f, 0.f, 0.f, 0.f};
            h0[mt][nt][0] = h0[mt][nt][1] = 0u;
            #pragma unroll
            for (int i = 0; i < 4; ++i) s[mt][nt][i] = 0.f;
        }

    // ================= recurrence =================
    // iteration t: acc = s_{t-1}@Wh^T (from GEMM t-1); lags: h0 = s_{t-2},
    // hist[t&1] = s_{t-3}, hist[(t+1)&1] = s_{t-4} (round-3-verified lag structure)
    for (int t = 1; t <= nsteps; ++t) {
        const int sA = t & 1, sB = sA ^ 1;
        #pragma unroll
        for (int mt = 0; mt < 4; ++mt) {
            uint4 hA = *(uint4*)&hist[((sA * 4 + mt) * 512 + tid) * 4];
            uint4 hB = *(uint4*)&hist[((sB * 4 + mt) * 512 + tid) * 4];
            uint4 nB;
            #pragma unroll
            for (int nt = 0; nt < 2; ++nt)
                #pragma unroll
                for (int pi = 0; pi < 2; ++pi) {
                    unsigned u1 = h0[mt][nt][pi];
                    unsigned u2 = ((unsigned*)&hA)[nt * 2 + pi];
                    unsigned u3 = ((unsigned*)&hB)[nt * 2 + pi];
                    unsigned ux = xpk[mt][nt][pi];
                    float p0 = acc[mt][nt][pi * 2] + bflo(ux)
                             + g1 * bflo(u1) + g2 * bflo(u2) + g3 * bflo(u3);
                    float p1 = acc[mt][nt][pi * 2 + 1] + bfhi(ux)
                             + g1 * bfhi(u1) + g2 * bfhi(u2) + g3 * bfhi(u3);
                    float so0 = s[mt][nt][pi * 2], so1 = s[mt][nt][pi * 2 + 1];
                    float sn0 = 0.5f * so0 + 0.5f * fast_tanh(p0);
                    float sn1 = 0.5f * so1 + 0.5f * fast_tanh(p1);
                    s[mt][nt][pi * 2] = sn0; s[mt][nt][pi * 2 + 1] = sn1;
                    ((unsigned*)&nB)[nt * 2 + pi] = u1;       // s_{t-2} becomes next s_{t-4} slot
                    h0[mt][nt][pi] = pk2(so0, so1);           // s_{t-1} for next iteration
                }
            *(uint4*)&hist[((sB * 4 + mt) * 512 + tid) * 4] = nB;
            acc[mt][0] = (f32x4){0.f, 0.f, 0.f, 0.f};
            acc[mt][1] = (f32x4){0.f, 0.f, 0.f, 0.f};
        }

        // partner must have consumed our piece of step t-1 before we overwrite it
        if (l == 0) { while (ldf(&cons[pb]) < t - 1) __builtin_amdgcn_s_sleep(1); }
        __builtin_amdgcn_sched_barrier(0);

        // scatter s_t into own LDS rows (kt = k0own + w per wave)
        #pragma unroll
        for (int mt = 0; mt < 4; ++mt)
            #pragma unroll
            for (int nt = 0; nt < 2; ++nt)
                #pragma unroll
                for (int i = 0; i < 4; ++i) {
                    int lam = q * 4 + i + 16 * (nt * 2 + (c >> 3));
                    sfrag[(mt * 16 + k0own + w) * 512 + lam * 8 + (c & 7)] = f2bf(s[mt][nt][i]);
                }
        __syncthreads();

        // coalesced copy own LDS region -> piece_me (16B/lane linear)
        #pragma unroll
        for (int j2 = 0; j2 < 4; ++j2) {
            int u = j2 * 512 + tid;                   // 16B unit, [0,2048)
            int mtg = u >> 9, ktl = (u >> 6) & 7, co = (u & 63) * 8;
            uint4 v = *(const uint4*)&sfrag[(mtg * 16 + k0own + ktl) * 512 + co];
            *(uint4*)&piece_me[(size_t)u * 8] = v;
        }

        if (t == nsteps) {
            WAITV0();
            __builtin_amdgcn_s_barrier();
            if (tid == 0) stf(&prod[bi], t);
            break;
        }

        // own-half GEMM (kt = k0own + j) hides the piece-store drain
        #pragma unroll
        for (int j = 0; j < 8; ++j) {
            const int kt = k0own + j;
            short8 a0 = *(const short8*)&sfrag[(0 * 16 + kt) * 512 + roff];
            short8 a1 = *(const short8*)&sfrag[(1 * 16 + kt) * 512 + roff];
            short8 a2 = *(const short8*)&sfrag[(2 * 16 + kt) * 512 + roff];
            short8 a3 = *(const short8*)&sfrag[(3 * 16 + kt) * 512 + roff];
            acc[0][0] = MFMA(a0, bw0[j], acc[0][0]); acc[0][1] = MFMA(a0, bw1[j], acc[0][1]);
            acc[1][0] = MFMA(a1, bw0[j], acc[1][0]); acc[1][1] = MFMA(a1, bw1[j], acc[1][1]);
            acc[2][0] = MFMA(a2, bw0[j], acc[2][0]); acc[2][1] = MFMA(a2, bw1[j], acc[2][1]);
            acc[3][0] = MFMA(a3, bw0[j], acc[3][0]); acc[3][1] = MFMA(a3, bw1[j], acc[3][1]);
        }

        WAITV0();                                     // piece stores L2-ack'd
        __builtin_amdgcn_s_barrier();
        if (tid == 0) stf(&prod[bi], t);

        // partner piece ready? stage it (linear gl_lds, L2 hit on same XCD)
        if (l == 0) { while (ldf(&prod[pb]) < t) __builtin_amdgcn_s_sleep(1); }
        __builtin_amdgcn_sched_barrier(0);
        {
            const int mtg = w >> 1;
            #pragma unroll
            for (int i2 = 0; i2 < 4; ++i2) {
                const int ktl = 4 * (w & 1) + i2;
                gl_lds16(piece_pa + (mtg * 8 + ktl) * 512 + l * 8,
                         &sfrag[(mtg * 16 + k0par + ktl) * 512]);
            }
        }
        __syncthreads();                              // drains gl_lds vmcnt + barrier
        if (tid == 0) stf(&cons[bi], t);

        // partner-half GEMM (kt = k0par + (j-8))
        #pragma unroll
        for (int j = 8; j < 16; ++j) {
            const int kt = k0par + (j - 8);
            short8 a0 = *(const short8*)&sfrag[(0 * 16 + kt) * 512 + roff];
            short8 a1 = *(const short8*)&sfrag[(1 * 16 + kt) * 512 + roff];
            short8 a2 = *(const short8*)&sfrag[(2 * 16 + kt) * 512 + roff];
            short8 a3 = *(const short8*)&sfrag[(3 * 16 + kt) * 512 + roff];
            acc[0][0] = MFMA(a0, bw0[j], acc[0][0]); acc[0][1] = MFMA(a0, bw1[j], acc[0][1]);
            acc[1][0] = MFMA(a1, bw0[j], acc[1][0]); acc[1][1] = MFMA(a1, bw1[j], acc[1][1]);
            acc[2][0] = MFMA(a2, bw0[j], acc[2][0]); acc[2][1] = MFMA(a2, bw1[j], acc[2][1]);
            acc[3][0] = MFMA(a3, bw0[j], acc[3][0]); acc[3][1] = MFMA(a3, bw1[j], acc[3][1]);
        }
    }

    // ================= head: out = s_final @ Head^T + Head_b =================
    if (l == 0) { while (ldf(&prod[pb]) < nsteps) __builtin_amdgcn_s_sleep(1); }
    __builtin_amdgcn_sched_barrier(0);
    {
        const int mtg = w >> 1;
        #pragma unroll
        for (int i2 = 0; i2 < 4; ++i2) {
            const int ktl = 4 * (w & 1) + i2;
            gl_lds16(piece_pa + (mtg * 8 + ktl) * 512 + l * 8,
                     &sfrag[(mtg * 16 + k0par + ktl) * 512]);
        }
    }
    // B regs <- Head panel (own-first kt order; wave w covers out cols [32w,32w+32))
    LOAD_PANEL(Hd_w, w * 32, (j < 8 ? k0own + j : k0par + (j - 8)));
    __syncthreads();

    f32x4 ah[2][2];
    ah[0][0] = (f32x4){0.f, 0.f, 0.f, 0.f}; ah[0][1] = (f32x4){0.f, 0.f, 0.f, 0.f};
    ah[1][0] = (f32x4){0.f, 0.f, 0.f, 0.f}; ah[1][1] = (f32x4){0.f, 0.f, 0.f, 0.f};
    #pragma unroll
    for (int j = 0; j < 16; ++j) {
        const int kt = (j < 8) ? k0own + j : k0par + (j - 8);
        short8 a0 = *(const short8*)&sfrag[((2 * mu + 0) * 16 + kt) * 512 + roff];
        short8 a1 = *(const short8*)&sfrag[((2 * mu + 1) * 16 + kt) * 512 + roff];
        ah[0][0] = MFMA(a0, bw0[j], ah[0][0]); ah[0][1] = MFMA(a0, bw1[j], ah[0][1]);
        ah[1][0] = MFMA(a1, bw0[j], ah[1][0]); ah[1][1] = MFMA(a1, bw1[j], ah[1][1]);
    }

    // out is not aliased by exchange slots anymore: store directly
    #pragma unroll
    for (int mtL = 0; mtL < 2; ++mtL)
        #pragma unroll
        for (int i = 0; i < 4; ++i) {
            int r = rows0 + 32 * mu + mtL * 16 + q * 4 + i;
            out[(size_t)r * 256 + w * 32 + c]      = ah[mtL][0][i] + hb0;
            out[(size_t)r * 256 + w * 32 + 16 + c] = ah[mtL][1][i] + hb1;
        }
}

extern "C" void kernel_launch(void* const* d_in, const int* in_sizes, int n_in,
                              void* d_out, int out_size, void* d_ws, size_t ws_size,
                              hipStream_t stream) {
    (void)n_in; (void)out_size;
    const float* x    = (const float*)d_in[0];
    const float* Wx_w = (const float*)d_in[1];
    const float* Wx_b = (const float*)d_in[2];
    const float* Wh_w = (const float*)d_in[3];
    const float* Wh_b = (const float*)d_in[4];
    const float* Hd_w = (const float*)d_in[5];
    const float* Hd_b = (const float*)d_in[6];
    const float* gma  = (const float*)d_in[7];
    const float* alp  = (const float*)d_in[8];
    const int*   stp  = (const int*)d_in[9];
    float* out = (float*)d_out;

    const size_t need = 4096 + (size_t)128 * 65536;   // flags + 128 groups x 64KB pieces
    if (ws_size < 4096) return;
    int* flags = (int*)d_ws;
    hipMemsetAsync(flags, 0, 4096, stream);           // prod[256] + cons[256], reset every launch

    // exchange slots in d_ws when it fits (L2-cacheable); else fall back to d_out rows
    unsigned short* pieces = (ws_size >= need)
        ? (unsigned short*)((char*)d_ws + 4096)
        : (unsigned short*)out;

    int batch = in_sizes[0] / 512;             // 8192
    int nblk  = batch / 32;                    // 256 blocks = 128 pairs
    toroidal<<<nblk, THREADS, 0, stream>>>(x, Wx_w, Wx_b, Wh_w, Wh_b, Hd_w, Hd_b,
                                           gma, alp, stp, out, flags, pieces);
}

// Round 7
// 574.097 us; speedup vs baseline: 3.3789x; 1.1200x over previous
//
#include <hip/hip_runtime.h>
#include <hip/hip_bf16.h>

typedef __attribute__((ext_vector_type(8))) short short8;
typedef __attribute__((ext_vector_type(4))) float f32x4;
typedef unsigned long long u64;

#define THREADS 512
#define MFMA(a, b, c) __builtin_amdgcn_mfma_f32_16x16x32_bf16((a), (b), (c), 0, 0, 0)

static __device__ __forceinline__ unsigned short f2bf(float x) {
    __hip_bfloat16 h = __float2bfloat16(x);
    return __builtin_bit_cast(unsigned short, h);
}
static __device__ __forceinline__ unsigned pk2(float a, float b) {
    return (unsigned)f2bf(a) | ((unsigned)f2bf(b) << 16);
}
static __device__ __forceinline__ float bflo(unsigned u) {
    unsigned v = u << 16; return __builtin_bit_cast(float, v);
}
static __device__ __forceinline__ float bfhi(unsigned u) {
    unsigned v = u & 0xffff0000u; return __builtin_bit_cast(float, v);
}
static __device__ __forceinline__ float fast_tanh(float x) {
    float e = __builtin_amdgcn_exp2f(x * 2.885390081777927f);
    float r = __builtin_amdgcn_rcpf(e + 1.0f);
    return fmaf(-2.0f, r, 1.0f);
}
static __device__ __forceinline__ short8 cvt8(float4 a, float4 b) {
    short8 r;
    r[0] = (short)f2bf(a.x); r[1] = (short)f2bf(a.y);
    r[2] = (short)f2bf(a.z); r[3] = (short)f2bf(a.w);
    r[4] = (short)f2bf(b.x); r[5] = (short)f2bf(b.y);
    r[6] = (short)f2bf(b.z); r[7] = (short)f2bf(b.w);
    return r;
}
// system-scope relaxed: plain loads/stores at the device coherence point
// (bypass L1+L2) — correct for ANY block->XCD placement; no wb/inv traffic.
static __device__ __forceinline__ u64 ld_sys(const u64* p) {
    return __hip_atomic_load(p, __ATOMIC_RELAXED, __HIP_MEMORY_SCOPE_SYSTEM);
}
static __device__ __forceinline__ void st_sys(u64* p, u64 v) {
    __hip_atomic_store(p, v, __ATOMIC_RELAXED, __HIP_MEMORY_SCOPE_SYSTEM);
}
static __device__ __forceinline__ int ldf(const int* p) {
    return __hip_atomic_load(p, __ATOMIC_RELAXED, __HIP_MEMORY_SCOPE_SYSTEM);
}
static __device__ __forceinline__ void stf(int* p, int v) {
    __hip_atomic_store(p, v, __ATOMIC_RELAXED, __HIP_MEMORY_SCOPE_SYSTEM);
}
#define WAITV0() asm volatile("s_waitcnt vmcnt(0)" ::: "memory")

// Load a 32-col x 512-k bf16 B-panel into registers.
// B-frag (16x16x32, round-1-verified): lane holds W[colbase + nt*16 + (l&15)][kt*32 + (l>>4)*8 + e]
#define LOAD_PANEL(W, CB, KT_OF_J)                                              \
    do {                                                                        \
        _Pragma("unroll")                                                       \
        for (int j = 0; j < 16; ++j) {                                          \
            const int kt_ = (KT_OF_J);                                          \
            const float* p0_ = (W) + (size_t)((CB) + c) * 512 + kt_ * 32 + q * 8;       \
            const float* p1_ = (W) + (size_t)((CB) + 16 + c) * 512 + kt_ * 32 + q * 8;  \
            float4 a0_ = *(const float4*)p0_, b0_ = *(const float4*)(p0_ + 4);  \
            float4 a1_ = *(const float4*)p1_, b1_ = *(const float4*)(p1_ + 4);  \
            bw0[j] = cvt8(a0_, b0_);                                            \
            bw1[j] = cvt8(a1_, b1_);                                            \
        }                                                                       \
    } while (0)

template<bool DBUF>
__global__ __attribute__((amdgpu_flat_work_group_size(512, 512), amdgpu_waves_per_eu(2, 2)))
void toroidal(
    const float* __restrict__ x,
    const float* __restrict__ Wx_w, const float* __restrict__ wxb,
    const float* __restrict__ Wh_w, const float* __restrict__ whb,
    const float* __restrict__ Hd_w, const float* __restrict__ hdb,
    const float* __restrict__ gamma_p, const float* __restrict__ alphas,
    const int* __restrict__ steps_p,
    float* __restrict__ out, int* __restrict__ flags,
    unsigned short* __restrict__ pieces, size_t slotStride /* shorts; 0 if single */)
{
    __shared__ __align__(16) unsigned short sfrag[32768];  // 64KB: A-frags [mt4][kt16][gran64][e8]
    __shared__ __align__(16) unsigned int   hist[16384];   // 64KB: 2 slots x 4 mt x 512 tid x uint4

    const int tid = threadIdx.x;
    const int w = tid >> 6;
    const int l = tid & 63;
    const int q = l >> 4;
    const int c = l & 15;

    const int bi  = blockIdx.x;
    const int mu  = (bi >> 3) & 1;                 // pair member
    const int grp = (bi & 7) * 16 + (bi >> 4);     // 0..127 (any placement is OK now)
    const int pb  = bi ^ 8;
    const int rows0 = grp * 64;

    int* prod = flags;
    int* cons = flags + 256;                       // only used when !DBUF

    unsigned short* pbase = pieces + (size_t)grp * 32768 + mu * 16384;        // mine
    const unsigned short* qbase = pieces + (size_t)grp * 32768 + (1 - mu) * 16384; // partner's

    const float gm = gamma_p[0];
    const float g1 = gm * alphas[0], g2 = gm * alphas[1], g3 = gm * alphas[2];
    const int nsteps = steps_p[0];

    const int colbase = mu * 256 + w * 32;         // this wave's hidden cols
    const float bias0 = wxb[colbase + c] + whb[colbase + c];
    const float bias1 = wxb[colbase + 16 + c] + whb[colbase + 16 + c];
    const float hb0 = hdb[w * 32 + c], hb1 = hdb[w * 32 + 16 + c];

    const int roff = l * 8;                        // linear A-read offset (shorts)
    const int k0own = 8 * mu, k0par = 8 * (1 - mu);

    short8 bw0[16], bw1[16];

    // ================= xproj: B regs <- Wx panel (natural kt order) =================
    LOAD_PANEL(Wx_w, colbase, j);

    f32x4 acc[4][2];
    #pragma unroll
    for (int mt = 0; mt < 4; ++mt) {
        acc[mt][0] = (f32x4){0.f, 0.f, 0.f, 0.f};
        acc[mt][1] = (f32x4){0.f, 0.f, 0.f, 0.f};
    }
    #pragma unroll
    for (int pass = 0; pass < 2; ++pass) {
        __syncthreads();
        #pragma unroll
        for (int j2 = 0; j2 < 8; ++j2) {
            int r = j2 * 8 + w;
            int kloc = l * 4;
            float4 v = *(const float4*)(x + (size_t)(rows0 + r) * 512 + pass * 256 + kloc);
            int mtx = r >> 4, ktl = kloc >> 5;
            int lane2 = (r & 15) + 16 * ((kloc >> 3) & 3);
            float* dst = (float*)sfrag + ((mtx * 8 + ktl) * 64 + lane2) * 8 + (kloc & 7);
            *(float4*)dst = v;
        }
        __syncthreads();
        #pragma unroll
        for (int j = 0; j < 8; ++j) {
            #pragma unroll
            for (int mt = 0; mt < 4; ++mt) {
                const float* fp = (const float*)sfrag + ((mt * 8 + j) * 64 + l) * 8;
                float4 u0 = *(const float4*)fp;
                float4 u1 = *(const float4*)(fp + 4);
                short8 a = cvt8(u0, u1);
                acc[mt][0] = MFMA(a, bw0[pass * 8 + j], acc[mt][0]);
                acc[mt][1] = MFMA(a, bw1[pass * 8 + j], acc[mt][1]);
            }
        }
    }
    __syncthreads();   // xproj reads done before step-1 scatter overwrites sfrag

    unsigned xpk[4][2][2];
    #pragma unroll
    for (int mt = 0; mt < 4; ++mt)
        #pragma unroll
        for (int nt = 0; nt < 2; ++nt) {
            float b = nt ? bias1 : bias0;
            xpk[mt][nt][0] = pk2(acc[mt][nt][0] + b, acc[mt][nt][1] + b);
            xpk[mt][nt][1] = pk2(acc[mt][nt][2] + b, acc[mt][nt][3] + b);
        }

    // ================= B regs <- Wh panel (own-half-first kt order) =================
    LOAD_PANEL(Wh_w, colbase, (j < 8 ? k0own + j : k0par + (j - 8)));

    uint4 z4 = {0u, 0u, 0u, 0u};
    #pragma unroll
    for (int sb = 0; sb < 8; ++sb) *(uint4*)&hist[(sb * 512 + tid) * 4] = z4;
    float s[4][2][4];
    unsigned h0[4][2][2];
    #pragma unroll
    for (int mt = 0; mt < 4; ++mt)
        #pragma unroll
        for (int nt = 0; nt < 2; ++nt) {
            acc[mt][nt] = (f32x4){0.f, 0.f, 0.f, 0.f};
            h0[mt][nt][0] = h0[mt][nt][1] = 0u;
            #pragma unroll
            for (int i = 0; i < 4; ++i) s[mt][nt][i] = 0.f;
        }

    // ================= recurrence =================
    for (int t = 1; t <= nsteps; ++t) {
        const int sA = t & 1, sB = sA ^ 1;
        #pragma unroll
        for (int mt = 0; mt < 4; ++mt) {
            uint4 hA = *(uint4*)&hist[((sA * 4 + mt) * 512 + tid) * 4];
            uint4 hB = *(uint4*)&hist[((sB * 4 + mt) * 512 + tid) * 4];
            uint4 nB;
            #pragma unroll
            for (int nt = 0; nt < 2; ++nt)
                #pragma unroll
                for (int pi = 0; pi < 2; ++pi) {
                    unsigned u1 = h0[mt][nt][pi];
                    unsigned u2 = ((unsigned*)&hA)[nt * 2 + pi];
                    unsigned u3 = ((unsigned*)&hB)[nt * 2 + pi];
                    unsigned ux = xpk[mt][nt][pi];
                    float p0 = acc[mt][nt][pi * 2] + bflo(ux)
                             + g1 * bflo(u1) + g2 * bflo(u2) + g3 * bflo(u3);
                    float p1 = acc[mt][nt][pi * 2 + 1] + bfhi(ux)
                             + g1 * bfhi(u1) + g2 * bfhi(u2) + g3 * bfhi(u3);
                    float so0 = s[mt][nt][pi * 2], so1 = s[mt][nt][pi * 2 + 1];
                    float sn0 = 0.5f * so0 + 0.5f * fast_tanh(p0);
                    float sn1 = 0.5f * so1 + 0.5f * fast_tanh(p1);
                    s[mt][nt][pi * 2] = sn0; s[mt][nt][pi * 2 + 1] = sn1;
                    ((unsigned*)&nB)[nt * 2 + pi] = u1;
                    h0[mt][nt][pi] = pk2(so0, so1);
                }
            *(uint4*)&hist[((sB * 4 + mt) * 512 + tid) * 4] = nB;
            acc[mt][0] = (f32x4){0.f, 0.f, 0.f, 0.f};
            acc[mt][1] = (f32x4){0.f, 0.f, 0.f, 0.f};
        }

        // scatter s_t into own sfrag rows (kt = k0own + w per wave)
        #pragma unroll
        for (int mt = 0; mt < 4; ++mt)
            #pragma unroll
            for (int nt = 0; nt < 2; ++nt)
                #pragma unroll
                for (int i = 0; i < 4; ++i) {
                    int lam = q * 4 + i + 16 * (nt * 2 + (c >> 3));
                    sfrag[(mt * 16 + k0own + w) * 512 + lam * 8 + (c & 7)] = f2bf(s[mt][nt][i]);
                }
        __syncthreads();

        if (!DBUF) {  // single buffer: partner must have consumed step t-1 slot
            if (l == 0) { while (ldf(&cons[pb]) < t - 1) __builtin_amdgcn_s_sleep(2); }
            __builtin_amdgcn_sched_barrier(0);
        }

        // copy-out own LDS region -> my piece slot (8 x u64 system stores, coalesced)
        u64* dstp = (u64*)(pbase + (DBUF ? (size_t)(t & 1) * slotStride : 0));
        #pragma unroll
        for (int i = 0; i < 8; ++i) {
            int u = i * 512 + tid;                 // 4096 u64 units = 32KB
            int mtg = u >> 10, ktl = (u >> 7) & 7, off = (u & 127) * 4;
            u64 v = *(const u64*)&sfrag[(mtg * 16 + k0own + ktl) * 512 + off];
            st_sys(dstp + u, v);
        }

        if (t == nsteps) {
            WAITV0();
            __builtin_amdgcn_s_barrier();
            if (tid == 0) stf(&prod[bi], t);
            break;
        }

        // own-half GEMM (hides the store drain)
        #pragma unroll
        for (int j = 0; j < 8; ++j) {
            const int kt = k0own + j;
            short8 a0 = *(const short8*)&sfrag[(0 * 16 + kt) * 512 + roff];
            short8 a1 = *(const short8*)&sfrag[(1 * 16 + kt) * 512 + roff];
            short8 a2 = *(const short8*)&sfrag[(2 * 16 + kt) * 512 + roff];
            short8 a3 = *(const short8*)&sfrag[(3 * 16 + kt) * 512 + roff];
            acc[0][0] = MFMA(a0, bw0[j], acc[0][0]); acc[0][1] = MFMA(a0, bw1[j], acc[0][1]);
            acc[1][0] = MFMA(a1, bw0[j], acc[1][0]); acc[1][1] = MFMA(a1, bw1[j], acc[1][1]);
            acc[2][0] = MFMA(a2, bw0[j], acc[2][0]); acc[2][1] = MFMA(a2, bw1[j], acc[2][1]);
            acc[3][0] = MFMA(a3, bw0[j], acc[3][0]); acc[3][1] = MFMA(a3, bw1[j], acc[3][1]);
        }

        WAITV0();                                  // piece stores at coherence point
        __builtin_amdgcn_s_barrier();
        if (tid == 0) stf(&prod[bi], t);

        // wait for partner piece t, then stage it into partner sfrag rows
        if (l == 0) { while (ldf(&prod[pb]) < t) __builtin_amdgcn_s_sleep(2); }
        __builtin_amdgcn_sched_barrier(0);
        {
            const u64* srcp = (const u64*)(qbase + (DBUF ? (size_t)(t & 1) * slotStride : 0));
            u64 tmp[8];
            #pragma unroll
            for (int i = 0; i < 8; ++i) tmp[i] = ld_sys(srcp + i * 512 + tid);
            #pragma unroll
            for (int i = 0; i < 8; ++i) {
                int u = i * 512 + tid;
                int mtg = u >> 10, ktl = (u >> 7) & 7, off = (u & 127) * 4;
                *(u64*)&sfrag[(mtg * 16 + k0par + ktl) * 512 + off] = tmp[i];
            }
        }
        __syncthreads();
        if (!DBUF) { if (tid == 0) stf(&cons[bi], t); }

        // partner-half GEMM
        #pragma unroll
        for (int j = 8; j < 16; ++j) {
            const int kt = k0par + (j - 8);
            short8 a0 = *(const short8*)&sfrag[(0 * 16 + kt) * 512 + roff];
            short8 a1 = *(const short8*)&sfrag[(1 * 16 + kt) * 512 + roff];
            short8 a2 = *(const short8*)&sfrag[(2 * 16 + kt) * 512 + roff];
            short8 a3 = *(const short8*)&sfrag[(3 * 16 + kt) * 512 + roff];
            acc[0][0] = MFMA(a0, bw0[j], acc[0][0]); acc[0][1] = MFMA(a0, bw1[j], acc[0][1]);
            acc[1][0] = MFMA(a1, bw0[j], acc[1][0]); acc[1][1] = MFMA(a1, bw1[j], acc[1][1]);
            acc[2][0] = MFMA(a2, bw0[j], acc[2][0]); acc[2][1] = MFMA(a2, bw1[j], acc[2][1]);
            acc[3][0] = MFMA(a3, bw0[j], acc[3][0]); acc[3][1] = MFMA(a3, bw1[j], acc[3][1]);
        }
    }

    // ================= head: out = s_final @ Head^T + Head_b =================
    if (l == 0) { while (ldf(&prod[pb]) < nsteps) __builtin_amdgcn_s_sleep(2); }
    __builtin_amdgcn_sched_barrier(0);
    {
        const u64* srcp = (const u64*)(qbase + (DBUF ? (size_t)(nsteps & 1) * slotStride : 0));
        u64 tmp[8];
        #pragma unroll
        for (int i = 0; i < 8; ++i) tmp[i] = ld_sys(srcp + i * 512 + tid);
        #pragma unroll
        for (int i = 0; i < 8; ++i) {
            int u = i * 512 + tid;
            int mtg = u >> 10, ktl = (u >> 7) & 7, off = (u & 127) * 4;
            *(u64*)&sfrag[(mtg * 16 + k0par + ktl) * 512 + off] = tmp[i];
        }
    }
    LOAD_PANEL(Hd_w, w * 32, (j < 8 ? k0own + j : k0par + (j - 8)));
    __syncthreads();
    if (!DBUF) { if (tid == 0) stf(&cons[bi], nsteps); }

    f32x4 ah[2][2];
    ah[0][0] = (f32x4){0.f, 0.f, 0.f, 0.f}; ah[0][1] = (f32x4){0.f, 0.f, 0.f, 0.f};
    ah[1][0] = (f32x4){0.f, 0.f, 0.f, 0.f}; ah[1][1] = (f32x4){0.f, 0.f, 0.f, 0.f};
    #pragma unroll
    for (int j = 0; j < 16; ++j) {
        const int kt = (j < 8) ? k0own + j : k0par + (j - 8);
        short8 a0 = *(const short8*)&sfrag[((2 * mu + 0) * 16 + kt) * 512 + roff];
        short8 a1 = *(const short8*)&sfrag[((2 * mu + 1) * 16 + kt) * 512 + roff];
        ah[0][0] = MFMA(a0, bw0[j], ah[0][0]); ah[0][1] = MFMA(a0, bw1[j], ah[0][1]);
        ah[1][0] = MFMA(a1, bw0[j], ah[1][0]); ah[1][1] = MFMA(a1, bw1[j], ah[1][1]);
    }

    if (!DBUF) {   // pieces may alias out: partner must finish reading its final piece
        if (l == 0) { while (ldf(&cons[pb]) < nsteps) __builtin_amdgcn_s_sleep(2); }
        __builtin_amdgcn_sched_barrier(0);
    }
    #pragma unroll
    for (int mtL = 0; mtL < 2; ++mtL)
        #pragma unroll
        for (int i = 0; i < 4; ++i) {
            int r = rows0 + 32 * mu + mtL * 16 + q * 4 + i;
            out[(size_t)r * 256 + w * 32 + c]      = ah[mtL][0][i] + hb0;
            out[(size_t)r * 256 + w * 32 + 16 + c] = ah[mtL][1][i] + hb1;
        }
}

extern "C" void kernel_launch(void* const* d_in, const int* in_sizes, int n_in,
                              void* d_out, int out_size, void* d_ws, size_t ws_size,
                              hipStream_t stream) {
    (void)n_in; (void)out_size;
    const float* x    = (const float*)d_in[0];
    const float* Wx_w = (const float*)d_in[1];
    const float* Wx_b = (const float*)d_in[2];
    const float* Wh_w = (const float*)d_in[3];
    const float* Wh_b = (const float*)d_in[4];
    const float* Hd_w = (const float*)d_in[5];
    const float* Hd_b = (const float*)d_in[6];
    const float* gma  = (const float*)d_in[7];
    const float* alp  = (const float*)d_in[8];
    const int*   stp  = (const int*)d_in[9];
    float* out = (float*)d_out;

    if (ws_size < 4096) return;
    int* flags = (int*)d_ws;
    hipMemsetAsync(flags, 0, 4096, stream);           // prod[256] + cons[256]

    const size_t SLOT = (size_t)8 << 20;              // 8 MB per piece slot
    int batch = in_sizes[0] / 512;                    // 8192
    int nblk  = batch / 32;                           // 256 blocks = 128 pairs

    if (ws_size >= 4096 + 2 * SLOT) {
        unsigned short* pieces = (unsigned short*)((char*)d_ws + 4096);
        toroidal<true><<<nblk, THREADS, 0, stream>>>(x, Wx_w, Wx_b, Wh_w, Wh_b, Hd_w, Hd_b,
                                                     gma, alp, stp, out, flags,
                                                     pieces, SLOT / 2);
    } else if (ws_size >= 4096 + SLOT) {
        unsigned short* pieces = (unsigned short*)((char*)d_ws + 4096);
        toroidal<false><<<nblk, THREADS, 0, stream>>>(x, Wx_w, Wx_b, Wh_w, Wh_b, Hd_w, Hd_b,
                                                      gma, alp, stp, out, flags,
                                                      pieces, 0);
    } else {
        toroidal<false><<<nblk, THREADS, 0, stream>>>(x, Wx_w, Wx_b, Wh_w, Wh_b, Hd_w, Hd_b,
                                                      gma, alp, stp, out, flags,
                                                      (unsigned short*)out, 0);
    }
}

// Round 8
// 542.821 us; speedup vs baseline: 3.5736x; 1.0576x over previous
//
#include <hip/hip_runtime.h>
#include <hip/hip_bf16.h>

typedef __attribute__((ext_vector_type(8))) short short8;
typedef __attribute__((ext_vector_type(4))) float f32x4;
typedef unsigned long long u64;

#define THREADS 512
#define MFMA(a, b, c) __builtin_amdgcn_mfma_f32_16x16x32_bf16((a), (b), (c), 0, 0, 0)

static __device__ __forceinline__ unsigned short f2bf(float x) {
    __hip_bfloat16 h = __float2bfloat16(x);
    return __builtin_bit_cast(unsigned short, h);
}
static __device__ __forceinline__ unsigned pk2(float a, float b) {
    return (unsigned)f2bf(a) | ((unsigned)f2bf(b) << 16);
}
static __device__ __forceinline__ float bflo(unsigned u) {
    unsigned v = u << 16; return __builtin_bit_cast(float, v);
}
static __device__ __forceinline__ float bfhi(unsigned u) {
    unsigned v = u & 0xffff0000u; return __builtin_bit_cast(float, v);
}
static __device__ __forceinline__ float fast_tanh(float x) {
    float e = __builtin_amdgcn_exp2f(x * 2.885390081777927f);
    float r = __builtin_amdgcn_rcpf(e + 1.0f);
    return fmaf(-2.0f, r, 1.0f);
}
static __device__ __forceinline__ short8 cvt8(float4 a, float4 b) {
    short8 r;
    r[0] = (short)f2bf(a.x); r[1] = (short)f2bf(a.y);
    r[2] = (short)f2bf(a.z); r[3] = (short)f2bf(a.w);
    r[4] = (short)f2bf(b.x); r[5] = (short)f2bf(b.y);
    r[6] = (short)f2bf(b.z); r[7] = (short)f2bf(b.w);
    return r;
}
static __device__ __forceinline__ u64 ld_sys(const u64* p) {
    return __hip_atomic_load(p, __ATOMIC_RELAXED, __HIP_MEMORY_SCOPE_SYSTEM);
}
static __device__ __forceinline__ void st_sys(u64* p, u64 v) {
    __hip_atomic_store(p, v, __ATOMIC_RELAXED, __HIP_MEMORY_SCOPE_SYSTEM);
}
static __device__ __forceinline__ int ldf(const int* p) {
    return __hip_atomic_load(p, __ATOMIC_RELAXED, __HIP_MEMORY_SCOPE_SYSTEM);
}
static __device__ __forceinline__ void stf(int* p, int v) {
    __hip_atomic_store(p, v, __ATOMIC_RELAXED, __HIP_MEMORY_SCOPE_SYSTEM);
}
static __device__ __forceinline__ u64 pku(unsigned lo, unsigned hi) {
    return (u64)lo | ((u64)hi << 32);
}
#define WAITV0()  asm volatile("s_waitcnt vmcnt(0)" ::: "memory")
#define WAITLG0() asm volatile("s_waitcnt lgkmcnt(0)" ::: "memory")
#define SCHEDB()  __builtin_amdgcn_sched_barrier(0)

// B-frag (16x16x32, round-1-verified): lane holds W[colbase + nt*16 + (l&15)][kt*32 + (l>>4)*8 + e]
#define LOAD_PANEL(W, CB, KT_OF_J)                                              \
    do {                                                                        \
        _Pragma("unroll")                                                       \
        for (int j = 0; j < 16; ++j) {                                          \
            const int kt_ = (KT_OF_J);                                          \
            const float* p0_ = (W) + (size_t)((CB) + c) * 512 + kt_ * 32 + q * 8;       \
            const float* p1_ = (W) + (size_t)((CB) + 16 + c) * 512 + kt_ * 32 + q * 8;  \
            float4 a0_ = *(const float4*)p0_, b0_ = *(const float4*)(p0_ + 4);  \
            float4 a1_ = *(const float4*)p1_, b1_ = *(const float4*)(p1_ + 4);  \
            bw0[j] = cvt8(a0_, b0_);                                            \
            bw1[j] = cvt8(a1_, b1_);                                            \
        }                                                                       \
    } while (0)

// elementwise for one row-half h (mt = 2h, 2h+1)
#define EW_HALF(h)                                                              \
    do {                                                                        \
        _Pragma("unroll")                                                       \
        for (int mt = 2*(h); mt < 2*(h) + 2; ++mt) {                            \
            uint4 hA = *(uint4*)&hist[((sA * 4 + mt) * 512 + tid) * 4];         \
            uint4 hB = *(uint4*)&hist[((sB * 4 + mt) * 512 + tid) * 4];         \
            uint4 nB;                                                           \
            _Pragma("unroll")                                                   \
            for (int nt = 0; nt < 2; ++nt)                                      \
                _Pragma("unroll")                                               \
                for (int pi = 0; pi < 2; ++pi) {                                \
                    unsigned u1 = h0[mt][nt][pi];                               \
                    unsigned u2 = ((unsigned*)&hA)[nt * 2 + pi];                \
                    unsigned u3 = ((unsigned*)&hB)[nt * 2 + pi];                \
                    unsigned ux = xpk[mt][nt][pi];                              \
                    float p0 = acc[mt][nt][pi * 2] + bflo(ux)                   \
                             + g1 * bflo(u1) + g2 * bflo(u2) + g3 * bflo(u3);   \
                    float p1 = acc[mt][nt][pi * 2 + 1] + bfhi(ux)               \
                             + g1 * bfhi(u1) + g2 * bfhi(u2) + g3 * bfhi(u3);   \
                    float so0 = s[mt][nt][pi * 2], so1 = s[mt][nt][pi * 2 + 1]; \
                    float sn0 = 0.5f * so0 + 0.5f * fast_tanh(p0);              \
                    float sn1 = 0.5f * so1 + 0.5f * fast_tanh(p1);              \
                    s[mt][nt][pi * 2] = sn0; s[mt][nt][pi * 2 + 1] = sn1;       \
                    ((unsigned*)&nB)[nt * 2 + pi] = u1;                         \
                    h0[mt][nt][pi] = pk2(so0, so1);                             \
                }                                                               \
            *(uint4*)&hist[((sB * 4 + mt) * 512 + tid) * 4] = nB;               \
            acc[mt][0] = (f32x4){0.f, 0.f, 0.f, 0.f};                           \
            acc[mt][1] = (f32x4){0.f, 0.f, 0.f, 0.f};                           \
        }                                                                       \
    } while (0)

// scatter s (half h) into own frag rows (kt = k0own + w), per-wave data only
#define SCATTER_HALF(h)                                                         \
    do {                                                                        \
        _Pragma("unroll")                                                       \
        for (int mt = 2*(h); mt < 2*(h) + 2; ++mt)                              \
            _Pragma("unroll")                                                   \
            for (int nt = 0; nt < 2; ++nt)                                      \
                _Pragma("unroll")                                               \
                for (int i = 0; i < 4; ++i) {                                   \
                    int lam = q * 4 + i + 16 * (nt * 2 + (c >> 3));             \
                    sfrag[(mt * 16 + k0own + w) * 512 + lam * 8 + (c & 7)] =    \
                        f2bf(s[mt][nt][i]);                                     \
                }                                                               \
    } while (0)

// copy this wave's 2 frags (half h) to its piece slot, drain, post per-wave flag
#define CP_POST(h, tt, myslot)                                                  \
    do {                                                                        \
        WAITLG0(); SCHEDB();                                                    \
        uint4 vA = *(const uint4*)&sfrag[((2*(h)) * 16 + k0own + w) * 512 + l * 8];     \
        uint4 vB = *(const uint4*)&sfrag[((2*(h)+1) * 16 + k0own + w) * 512 + l * 8];   \
        u64* dA = (u64*)((myslot) + ((2*(h)) * 8 + w) * 512 + l * 8);           \
        u64* dB = (u64*)((myslot) + ((2*(h)+1) * 8 + w) * 512 + l * 8);         \
        st_sys(dA, pku(vA.x, vA.y)); st_sys(dA + 1, pku(vA.z, vA.w));           \
        st_sys(dB, pku(vB.x, vB.y)); st_sys(dB + 1, pku(vB.z, vB.w));           \
        WAITV0();                                                               \
        if (l == 0) stf(&prodw[bi * 8 + w], 2 * (tt) + (h));                    \
    } while (0)

// partner-half GEMM for row-half h
#define PGEMM_HALF(h)                                                           \
    do {                                                                        \
        _Pragma("unroll")                                                       \
        for (int j = 0; j < 8; ++j) {                                           \
            const int kt = k0par + j;                                           \
            short8 aL = *(const short8*)&sfrag[((2*(h)) * 16 + kt) * 512 + roff];       \
            short8 aH = *(const short8*)&sfrag[((2*(h)+1) * 16 + kt) * 512 + roff];     \
            acc[2*(h)][0]   = MFMA(aL, bw0[8 + j], acc[2*(h)][0]);              \
            acc[2*(h)][1]   = MFMA(aL, bw1[8 + j], acc[2*(h)][1]);              \
            acc[2*(h)+1][0] = MFMA(aH, bw0[8 + j], acc[2*(h)+1][0]);            \
            acc[2*(h)+1][1] = MFMA(aH, bw1[8 + j], acc[2*(h)+1][1]);            \
        }                                                                       \
    } while (0)

template<bool DBUF>
__global__ __attribute__((amdgpu_flat_work_group_size(512, 512), amdgpu_waves_per_eu(2, 2)))
void toroidal(
    const float* __restrict__ x,
    const float* __restrict__ Wx_w, const float* __restrict__ wxb,
    const float* __restrict__ Wh_w, const float* __restrict__ whb,
    const float* __restrict__ Hd_w, const float* __restrict__ hdb,
    const float* __restrict__ gamma_p, const float* __restrict__ alphas,
    const int* __restrict__ steps_p,
    float* __restrict__ out, int* __restrict__ flags,
    unsigned short* __restrict__ slotE, unsigned short* __restrict__ slotO)
{
    __shared__ __align__(16) unsigned short sfrag[32768];  // 64KB A-frags [mt4][kt16][lane64][e8]
    __shared__ __align__(16) unsigned int   hist[16384];   // 64KB 2 slots x 4 mt x 512 tid x uint4

    const int tid = threadIdx.x;
    const int w = tid >> 6;
    const int l = tid & 63;
    const int q = l >> 4;
    const int c = l & 15;

    const int bi  = blockIdx.x;
    const int mu  = (bi >> 3) & 1;
    const int grp = (bi & 7) * 16 + (bi >> 4);
    const int pb  = bi ^ 8;
    const int rows0 = grp * 64;

    int* prodw = flags;                 // [256 blocks][8 waves]
    int* consw = flags + 2048;          // per-wave consume flags (only !DBUF)
    int* consB = flags + 4096;          // head-phase block flags (only !DBUF)

    unsigned short* myE = slotE + (size_t)grp * 32768 + mu * 16384;
    unsigned short* myO = slotO + (size_t)grp * 32768 + mu * 16384;
    const unsigned short* qE = slotE + (size_t)grp * 32768 + (1 - mu) * 16384;
    const unsigned short* qO = slotO + (size_t)grp * 32768 + (1 - mu) * 16384;

    const float gm = gamma_p[0];
    const float g1 = gm * alphas[0], g2 = gm * alphas[1], g3 = gm * alphas[2];
    const int nsteps = steps_p[0];

    const int colbase = mu * 256 + w * 32;
    const float bias0 = wxb[colbase + c] + whb[colbase + c];
    const float bias1 = wxb[colbase + 16 + c] + whb[colbase + 16 + c];
    const float hb0 = hdb[w * 32 + c], hb1 = hdb[w * 32 + 16 + c];

    const int roff = l * 8;
    const int k0own = 8 * mu, k0par = 8 * (1 - mu);

    short8 bw0[16], bw1[16];

    // ================= xproj (unchanged, verified) =================
    LOAD_PANEL(Wx_w, colbase, j);

    f32x4 acc[4][2];
    #pragma unroll
    for (int mt = 0; mt < 4; ++mt) {
        acc[mt][0] = (f32x4){0.f, 0.f, 0.f, 0.f};
        acc[mt][1] = (f32x4){0.f, 0.f, 0.f, 0.f};
    }
    #pragma unroll
    for (int pass = 0; pass < 2; ++pass) {
        __syncthreads();
        #pragma unroll
        for (int j2 = 0; j2 < 8; ++j2) {
            int r = j2 * 8 + w;
            int kloc = l * 4;
            float4 v = *(const float4*)(x + (size_t)(rows0 + r) * 512 + pass * 256 + kloc);
            int mtx = r >> 4, ktl = kloc >> 5;
            int lane2 = (r & 15) + 16 * ((kloc >> 3) & 3);
            float* dst = (float*)sfrag + ((mtx * 8 + ktl) * 64 + lane2) * 8 + (kloc & 7);
            *(float4*)dst = v;
        }
        __syncthreads();
        #pragma unroll
        for (int j = 0; j < 8; ++j) {
            #pragma unroll
            for (int mt = 0; mt < 4; ++mt) {
                const float* fp = (const float*)sfrag + ((mt * 8 + j) * 64 + l) * 8;
                float4 u0 = *(const float4*)fp;
                float4 u1 = *(const float4*)(fp + 4);
                short8 a = cvt8(u0, u1);
                acc[mt][0] = MFMA(a, bw0[pass * 8 + j], acc[mt][0]);
                acc[mt][1] = MFMA(a, bw1[pass * 8 + j], acc[mt][1]);
            }
        }
    }
    __syncthreads();

    unsigned xpk[4][2][2];
    #pragma unroll
    for (int mt = 0; mt < 4; ++mt)
        #pragma unroll
        for (int nt = 0; nt < 2; ++nt) {
            float b = nt ? bias1 : bias0;
            xpk[mt][nt][0] = pk2(acc[mt][nt][0] + b, acc[mt][nt][1] + b);
            xpk[mt][nt][1] = pk2(acc[mt][nt][2] + b, acc[mt][nt][3] + b);
        }

    // ================= Wh panel (own-half-first kt order) =================
    LOAD_PANEL(Wh_w, colbase, (j < 8 ? k0own + j : k0par + (j - 8)));

    uint4 z4 = {0u, 0u, 0u, 0u};
    #pragma unroll
    for (int sb = 0; sb < 8; ++sb) *(uint4*)&hist[(sb * 512 + tid) * 4] = z4;
    float s[4][2][4];
    unsigned h0[4][2][2];
    #pragma unroll
    for (int mt = 0; mt < 4; ++mt)
        #pragma unroll
        for (int nt = 0; nt < 2; ++nt) {
            acc[mt][nt] = (f32x4){0.f, 0.f, 0.f, 0.f};
            h0[mt][nt][0] = h0[mt][nt][1] = 0u;
            #pragma unroll
            for (int i = 0; i < 4; ++i) s[mt][nt][i] = 0.f;
        }

    // consumer mapping constants: wave w consumes frags (mt=2h+(w>>2), ktl0..ktl0+1)
    const int cmt_lo = (w >> 2);            // + 2h
    const int ktl0 = (2 * w) & 7;

    // ================= recurrence =================
    for (int t = 1; t <= nsteps; ++t) {
        const int sA = t & 1, sB = sA ^ 1;
        unsigned short* us = (t & 1) ? myO : myE;
        const unsigned short* qs = (t & 1) ? qO : qE;

        if (!DBUF && t >= 2) {   // single slot: wait until partner consumed t-1 piece
            const int wA = (w & 6) >> 1, wB = wA + 4, tv = 2 * (t - 1) + 1;
            if (l == 0) {
                while (ldf(&consw[pb * 8 + wA]) < tv || ldf(&consw[pb * 8 + wB]) < tv)
                    __builtin_amdgcn_s_sleep(1);
            }
            SCHEDB();
        }

        EW_HALF(0);
        SCATTER_HALF(0);
        CP_POST(0, t, us);
        EW_HALF(1);
        SCATTER_HALF(1);
        CP_POST(1, t, us);

        if (t == nsteps) break;

        __syncthreads();                               // BAR_A: all scatters visible

        // own-half GEMM (all 4 mt, kt = k0own + j)
        #pragma unroll
        for (int j = 0; j < 8; ++j) {
            const int kt = k0own + j;
            short8 a0 = *(const short8*)&sfrag[(0 * 16 + kt) * 512 + roff];
            short8 a1 = *(const short8*)&sfrag[(1 * 16 + kt) * 512 + roff];
            short8 a2 = *(const short8*)&sfrag[(2 * 16 + kt) * 512 + roff];
            short8 a3 = *(const short8*)&sfrag[(3 * 16 + kt) * 512 + roff];
            acc[0][0] = MFMA(a0, bw0[j], acc[0][0]); acc[0][1] = MFMA(a0, bw1[j], acc[0][1]);
            acc[1][0] = MFMA(a1, bw0[j], acc[1][0]); acc[1][1] = MFMA(a1, bw1[j], acc[1][1]);
            acc[2][0] = MFMA(a2, bw0[j], acc[2][0]); acc[2][1] = MFMA(a2, bw1[j], acc[2][1]);
            acc[3][0] = MFMA(a3, bw0[j], acc[3][0]); acc[3][1] = MFMA(a3, bw1[j], acc[3][1]);
        }

        // ---- poll + consume half 0 ----
        {
            const int mt = cmt_lo;                      // 2*0 + (w>>2)
            const int v = 2 * t;
            if (l == 0) {
                for (;;) {
                    u64 f = ld_sys((const u64*)&prodw[pb * 8 + ktl0]);
                    if ((int)(f & 0xffffffffu) >= v && (int)(f >> 32) >= v) break;
                    __builtin_amdgcn_s_sleep(1);
                }
            }
            SCHEDB();
            const u64* s0 = (const u64*)(qs + (mt * 8 + ktl0) * 512 + l * 8);
            const u64* s1 = (const u64*)(qs + (mt * 8 + ktl0 + 1) * 512 + l * 8);
            u64 a0 = ld_sys(s0), a1 = ld_sys(s0 + 1);
            u64 b0 = ld_sys(s1), b1 = ld_sys(s1 + 1);
            uint4 wA = { (unsigned)a0, (unsigned)(a0 >> 32), (unsigned)a1, (unsigned)(a1 >> 32) };
            uint4 wB = { (unsigned)b0, (unsigned)(b0 >> 32), (unsigned)b1, (unsigned)(b1 >> 32) };
            *(uint4*)&sfrag[(mt * 16 + k0par + ktl0) * 512 + l * 8]       = wA;
            *(uint4*)&sfrag[(mt * 16 + k0par + ktl0 + 1) * 512 + l * 8]   = wB;
        }
        __syncthreads();                               // BAR_B: h0 frags ready

        // ---- poll half 1 + issue loads (latency hides under pG0) ----
        u64 c0, c1, d0, d1;
        {
            const int mt = 2 + cmt_lo;
            const int v = 2 * t + 1;
            if (l == 0) {
                for (;;) {
                    u64 f = ld_sys((const u64*)&prodw[pb * 8 + ktl0]);
                    if ((int)(f & 0xffffffffu) >= v && (int)(f >> 32) >= v) break;
                    __builtin_amdgcn_s_sleep(1);
                }
            }
            SCHEDB();
            const u64* s0 = (const u64*)(qs + (mt * 8 + ktl0) * 512 + l * 8);
            const u64* s1 = (const u64*)(qs + (mt * 8 + ktl0 + 1) * 512 + l * 8);
            c0 = ld_sys(s0); c1 = ld_sys(s0 + 1);
            d0 = ld_sys(s1); d1 = ld_sys(s1 + 1);
        }

        PGEMM_HALF(0);                                 // overlaps the h1 loads

        {   // write h1 frags to LDS
            const int mt = 2 + cmt_lo;
            uint4 wA = { (unsigned)c0, (unsigned)(c0 >> 32), (unsigned)c1, (unsigned)(c1 >> 32) };
            uint4 wB = { (unsigned)d0, (unsigned)(d0 >> 32), (unsigned)d1, (unsigned)(d1 >> 32) };
            *(uint4*)&sfrag[(mt * 16 + k0par + ktl0) * 512 + l * 8]     = wA;
            *(uint4*)&sfrag[(mt * 16 + k0par + ktl0 + 1) * 512 + l * 8] = wB;
        }
        __syncthreads();                               // BAR_C: h1 frags ready

        PGEMM_HALF(1);

        if (!DBUF) { if (l == 0) stf(&consw[bi * 8 + w], 2 * t + 1); }
    }

    // ================= head =================
    {   // poll all 4 producers of this wave's head frags for final (both halves)
        const int fb = 4 * (w & 1);
        const int v = 2 * nsteps + 1;
        if (l == 0) {
            for (;;) {
                u64 f0 = ld_sys((const u64*)&prodw[pb * 8 + fb]);
                u64 f1 = ld_sys((const u64*)&prodw[pb * 8 + fb + 2]);
                if ((int)(f0 & 0xffffffffu) >= v && (int)(f0 >> 32) >= v &&
                    (int)(f1 & 0xffffffffu) >= v && (int)(f1 >> 32) >= v) break;
                __builtin_amdgcn_s_sleep(1);
            }
        }
        SCHEDB();
        const unsigned short* qs = (nsteps & 1) ? qO : qE;
        const int mtg = w >> 1;
        #pragma unroll
        for (int i2 = 0; i2 < 4; ++i2) {
            const int ktl = fb + i2;
            const u64* sp = (const u64*)(qs + (mtg * 8 + ktl) * 512 + l * 8);
            u64 a0 = ld_sys(sp), a1 = ld_sys(sp + 1);
            uint4 vv = { (unsigned)a0, (unsigned)(a0 >> 32), (unsigned)a1, (unsigned)(a1 >> 32) };
            *(uint4*)&sfrag[(mtg * 16 + k0par + ktl) * 512 + l * 8] = vv;
        }
    }
    LOAD_PANEL(Hd_w, w * 32, (j < 8 ? k0own + j : k0par + (j - 8)));
    __syncthreads();
    if (!DBUF) { if (tid == 0) stf(&consB[bi], 1); }

    f32x4 ah[2][2];
    ah[0][0] = (f32x4){0.f, 0.f, 0.f, 0.f}; ah[0][1] = (f32x4){0.f, 0.f, 0.f, 0.f};
    ah[1][0] = (f32x4){0.f, 0.f, 0.f, 0.f}; ah[1][1] = (f32x4){0.f, 0.f, 0.f, 0.f};
    #pragma unroll
    for (int j = 0; j < 16; ++j) {
        const int kt = (j < 8) ? k0own + j : k0par + (j - 8);
        short8 a0 = *(const short8*)&sfrag[((2 * mu + 0) * 16 + kt) * 512 + roff];
        short8 a1 = *(const short8*)&sfrag[((2 * mu + 1) * 16 + kt) * 512 + roff];
        ah[0][0] = MFMA(a0, bw0[j], ah[0][0]); ah[0][1] = MFMA(a0, bw1[j], ah[0][1]);
        ah[1][0] = MFMA(a1, bw0[j], ah[1][0]); ah[1][1] = MFMA(a1, bw1[j], ah[1][1]);
    }

    if (!DBUF) {   // pieces alias out: partner must finish reading before we overwrite
        if (l == 0) { while (ldf(&consB[pb]) < 1) __builtin_amdgcn_s_sleep(1); }
        SCHEDB();
    }
    #pragma unroll
    for (int mtL = 0; mtL < 2; ++mtL)
        #pragma unroll
        for (int i = 0; i < 4; ++i) {
            int r = rows0 + 32 * mu + mtL * 16 + q * 4 + i;
            out[(size_t)r * 256 + w * 32 + c]      = ah[mtL][0][i] + hb0;
            out[(size_t)r * 256 + w * 32 + 16 + c] = ah[mtL][1][i] + hb1;
        }
}

extern "C" void kernel_launch(void* const* d_in, const int* in_sizes, int n_in,
                              void* d_out, int out_size, void* d_ws, size_t ws_size,
                              hipStream_t stream) {
    (void)n_in; (void)out_size;
    const float* x    = (const float*)d_in[0];
    const float* Wx_w = (const float*)d_in[1];
    const float* Wx_b = (const float*)d_in[2];
    const float* Wh_w = (const float*)d_in[3];
    const float* Wh_b = (const float*)d_in[4];
    const float* Hd_w = (const float*)d_in[5];
    const float* Hd_b = (const float*)d_in[6];
    const float* gma  = (const float*)d_in[7];
    const float* alp  = (const float*)d_in[8];
    const int*   stp  = (const int*)d_in[9];
    float* out = (float*)d_out;

    const size_t FB   = 20480;                       // flags region (17408 B used)
    const size_t SLOT = (size_t)8 * 1024 * 1024;     // one piece set = 8 MB
    if (ws_size < FB) return;
    int* flags = (int*)d_ws;
    hipMemsetAsync(flags, 0, FB, stream);

    int batch = in_sizes[0] / 512;                   // 8192
    int nblk  = batch / 32;                          // 256 blocks = 128 pairs

    if (ws_size >= FB + 2 * SLOT) {
        unsigned short* e = (unsigned short*)((char*)d_ws + FB);
        unsigned short* o = e + SLOT / 2;
        toroidal<true><<<nblk, THREADS, 0, stream>>>(x, Wx_w, Wx_b, Wh_w, Wh_b, Hd_w, Hd_b,
                                                     gma, alp, stp, out, flags, e, o);
    } else if (ws_size >= FB + SLOT) {
        // even slot in ws (final pieces land here), odd slot overlays out (consumed before head writes)
        unsigned short* e = (unsigned short*)((char*)d_ws + FB);
        toroidal<true><<<nblk, THREADS, 0, stream>>>(x, Wx_w, Wx_b, Wh_w, Wh_b, Hd_w, Hd_b,
                                                     gma, alp, stp, out, flags,
                                                     e, (unsigned short*)out);
    } else {
        // single slot in out + explicit consume handshakes
        toroidal<false><<<nblk, THREADS, 0, stream>>>(x, Wx_w, Wx_b, Wh_w, Wh_b, Hd_w, Hd_b,
                                                      gma, alp, stp, out, flags,
                                                      (unsigned short*)out, (unsigned short*)out);
    }
}